// Round 10
// baseline (369.083 us; speedup 1.0000x reference)
//
#include <hip/hip_runtime.h>
#include <stdint.h>

// PRNG variant: 1 = jax_threefry_partitionable=True (JAX >= 0.4.36 default)
#ifndef JAX_THREEFRY_PARTITIONABLE
#define JAX_THREEFRY_PARTITIONABLE 1
#endif

#define N_SAMP 2000
#define L_VAR  10000
#define R_PERM 200
#define DOF_D  1989.0   // N - K - 1

#define KPAD   2048     // padded K (samples) for MFMA path
#define LPAD   10048    // padded L (157*64)
#define RPAD   256      // padded R

// ---------------- workspace layout (bytes) ----------------
// ---- fallback region (layout identical to round-2 kernel) ----
#define OFF_PKEYS  0UL
#define OFF_MI     1664UL
#define OFF_MINP   2464UL
#define OFF_XT     2560UL
#define OFF_XTGP   82560UL     // fallback only
#define OFF_GGP    2082560UL   // fallback only
#define OFF_GG     2282560UL
#define OFF_YTY    2322560UL
#define OFF_S      2323392UL
#define OFF_YT     2324224UL   // fallback only (big path overlaps with YHI)
#define WS_OLD     3924224UL
// ---- big-ws (MFMA) region; overlaps fallback-only scratch ----
#define OFF_GGP2   82560UL     // float[16][10048] = 643,072 (over fallback XTGP)
#define OFF_RGG    725632UL    // float[10048]
#define OFF_YHI    2324224UL   // u16[256][2048] = 1,048,576 (over fallback YT)
#define OFF_XTGP2  3924224UL   // float[16][10][10048] = 6,430,720
#define OFF_YLO    10354944UL  // u16[256][2048]
#define OFF_GTHI   11403520UL  // u16[10048][2048] = 41,156,608
#define OFF_GTLO   52560128UL  // u16[10048][2048] -> ends 93,716,736
#define WS_BIG     95186432UL  // known good (rounds 3-5 ran big path)

typedef __attribute__((ext_vector_type(8))) short short8v;   // 8 bf16
typedef __attribute__((ext_vector_type(4))) float float4v;   // MFMA acc

// ---------------- threefry2x32, JAX-exact ----------------
__device__ __forceinline__ uint32_t rotl32(uint32_t v, int d) {
  return (v << d) | (v >> (32 - d));
}
__device__ __forceinline__ uint2 tf2(uint32_t k0, uint32_t k1, uint32_t x0, uint32_t x1) {
  uint32_t ks2 = k0 ^ k1 ^ 0x1BD11BDAu;
  x0 += k0; x1 += k1;
#define TF4(a,b,c,d) \
  x0 += x1; x1 = rotl32(x1,a); x1 ^= x0; \
  x0 += x1; x1 = rotl32(x1,b); x1 ^= x0; \
  x0 += x1; x1 = rotl32(x1,c); x1 ^= x0; \
  x0 += x1; x1 = rotl32(x1,d); x1 ^= x0;
  TF4(13,15,26,6)  x0 += k1;  x1 += ks2 + 1u;
  TF4(17,29,16,24) x0 += ks2; x1 += k0 + 2u;
  TF4(13,15,26,6)  x0 += k0;  x1 += k1 + 3u;
  TF4(17,29,16,24) x0 += k1;  x1 += ks2 + 4u;
  TF4(13,15,26,6)  x0 += ks2; x1 += k0 + 5u;
#undef TF4
  return make_uint2(x0, x1);
}

// single-thread fallback key chain
__device__ __forceinline__ void gen_pkeys(const int* seedp, unsigned* pkeys) {
  uint32_t khi = 0u, klo = (uint32_t)(*seedp);
  for (int r = 0; r < R_PERM; ++r) {
#if JAX_THREEFRY_PARTITIONABLE
    uint2 pk = tf2(khi, klo, 0u, 1u);
    uint2 nk = tf2(khi, klo, 0u, 0u);
#else
    uint2 t0 = tf2(khi, klo, 0u, 2u);
    uint2 t1 = tf2(khi, klo, 1u, 3u);
    uint2 nk = make_uint2(t0.x, t1.x);
    uint2 pk = make_uint2(t0.y, t1.y);
#endif
    pkeys[2 * r] = pk.x; pkeys[2 * r + 1] = pk.y;
    khi = nk.x; klo = nk.y;
  }
}

// ---------------- block reduce (256 threads, for k6) ----------------
__device__ __forceinline__ double breduce_add(double v, double* red, int tid) {
  red[tid] = v; __syncthreads();
  for (int off = 128; off > 0; off >>= 1) {
    if (tid < off) red[tid] += red[tid + off];
    __syncthreads();
  }
  double r = red[0]; __syncthreads();
  return r;
}

// ---------------- special functions (double) ----------------
__device__ double dg_digamma(double x) {
  if (!(x > 0.0)) return __builtin_nan("");
  double r = 0.0;
  while (x < 8.0) { r -= 1.0 / x; x += 1.0; }
  double t = 1.0 / x, t2 = t * t;
  double ser = t2 * (1.0/12.0 - t2*(1.0/120.0 - t2*(1.0/252.0 - t2*(1.0/240.0 - t2*(1.0/132.0)))));
  return r + log(x) - 0.5 * t - ser;
}
__device__ double dg_trigamma(double x) {
  if (!(x > 0.0)) return __builtin_nan("");
  double r = 0.0;
  while (x < 8.0) { r += 1.0 / (x * x); x += 1.0; }
  double t = 1.0 / x, t2 = t * t;
  double P = 1.0/6.0 - t2*(1.0/30.0 - t2*(1.0/42.0 - t2*(1.0/30.0 - t2*(5.0/66.0))));
  return r + t + 0.5 * t2 + t * t2 * P;
}
__device__ double dg_tetragamma(double x) {
  if (!(x > 0.0)) return __builtin_nan("");
  double r = 0.0;
  while (x < 8.0) { r -= 2.0 / (x * x * x); x += 1.0; }
  double t = 1.0 / x, t2 = t * t;
  double Q = 1.0 + t + 0.5*t2 - t2*t2*(1.0/6.0 - t2*(1.0/6.0 - t2*(3.0/10.0)));
  return r - t2 * Q;
}
__device__ double betacf_d(double a, double b, double x) {
  const double FPMIN = 1e-300, EPS = 3e-16;
  double qab = a + b, qap = a + 1.0, qam = a - 1.0;
  double c = 1.0, d = 1.0 - qab * x / qap;
  if (fabs(d) < FPMIN) d = FPMIN;
  d = 1.0 / d; double h = d;
  for (int m = 1; m <= 300; ++m) {
    int m2 = 2 * m;
    double aa = m * (b - m) * x / ((qam + m2) * (a + m2));
    d = 1.0 + aa * d; if (fabs(d) < FPMIN) d = FPMIN;
    c = 1.0 + aa / c; if (fabs(c) < FPMIN) c = FPMIN;
    d = 1.0 / d; double del = d * c; h *= del;
    aa = -(a + m) * (qab + m) * x / ((a + m2) * (qap + m2));
    d = 1.0 + aa * d; if (fabs(d) < FPMIN) d = FPMIN;
    c = 1.0 + aa / c; if (fabs(c) < FPMIN) c = FPMIN;
    d = 1.0 / d; del = d * c; h *= del;
    if (fabs(del - 1.0) < EPS) break;
  }
  return h;
}
__device__ double betainc_d(double a, double b, double x) {
  if (!(x > 0.0)) return 0.0;
  if (x >= 1.0) return 1.0;
  double lnbt = lgamma(a + b) - lgamma(a) - lgamma(b) + a * log(x) + b * log1p(-x);
  double bt = exp(lnbt);
  if (x < (a + 1.0) / (a + b + 2.0)) return bt * betacf_d(a, b, x) / a;
  else return 1.0 - bt * betacf_d(b, a, 1.0 - x) / b;
}

__device__ __forceinline__ void tri_ab(int q, int& a, int& b) {
  int aa = 0, rem = q;
  while (rem >= 10 - aa) { rem -= 10 - aa; ++aa; }
  a = aa; b = aa + rem;
}

// split fp32 -> bf16 hi + bf16 lo (truncation split)
__device__ __forceinline__ void bf16split(float f, unsigned short& h, unsigned short& l) {
  unsigned u = __float_as_uint(f);
  h = (unsigned short)(u >> 16);
  float rem = f - __uint_as_float(u & 0xFFFF0000u);
  l = (unsigned short)(__float_as_uint(rem) >> 16);
}

// per-element sort key (matches original fill_keys exactly)
__device__ __forceinline__ unsigned long long keyfor(uint32_t kx, uint32_t ky, int e) {
  if (e >= N_SAMP) return ~0ull;
#if JAX_THREEFRY_PARTITIONABLE
  uint2 o = tf2(kx, ky, 0u, (uint32_t)e);
  uint32_t bits = o.x ^ o.y;
  return (((unsigned long long)bits) << 11) | (unsigned long long)e;
#else
  uint2 o = (e < 1000) ? tf2(kx, ky, (uint32_t)e, (uint32_t)(1000 + e))
                       : tf2(kx, ky, (uint32_t)(e - 1000), (uint32_t)e);
  uint32_t bits = (e < 1000) ? o.x : o.y;
  return (((unsigned long long)bits) << 11) | (unsigned long long)e;
#endif
}

// ====== K1: XtX inverse (LDS GJ), min(obs_p), X^T, bf16-Y pad-zero ============
// Round-3: XtX phase coalesced -- thread t owns rows i = t+256*j, float2 loads,
// all 55 upper-tri products in registers, wave-shuffle reduce.
__global__ __launch_bounds__(256) void k1_setup(
    const float* __restrict__ X, const float* __restrict__ obs_p,
    float* __restrict__ Xt, double* __restrict__ Mi, float* __restrict__ minp,
    unsigned short* __restrict__ yhi, unsigned short* __restrict__ ylo) {
  int tid = threadIdx.x;
  if (blockIdx.x == 0) {
    __shared__ double wsum[4][55];
    __shared__ double xtx_sh[55];
    __shared__ double A[10][21];
    __shared__ int piv_sh;
    __shared__ double pv_sh;
    int wave = tid >> 6, lane = tid & 63;

    double acc[55];
    #pragma unroll
    for (int q = 0; q < 55; ++q) acc[q] = 0.0;
    for (int i = tid; i < N_SAMP; i += 256) {
      float xv[10];
      #pragma unroll
      for (int k = 0; k < 5; ++k) {
        float2 t2 = *(const float2*)(X + i * 10 + 2 * k);
        xv[2 * k] = t2.x; xv[2 * k + 1] = t2.y;
      }
      int q = 0;
      #pragma unroll
      for (int a = 0; a < 10; ++a)
        #pragma unroll
        for (int b = a; b < 10; ++b)
          acc[q++] += (double)xv[a] * (double)xv[b];
    }
    #pragma unroll
    for (int q = 0; q < 55; ++q) {
      double v = acc[q];
      #pragma unroll
      for (int off = 32; off > 0; off >>= 1) v += __shfl_xor(v, off, 64);
      if (lane == 0) wsum[wave][q] = v;
    }
    __syncthreads();
    if (tid < 55) xtx_sh[tid] = wsum[0][tid] + wsum[1][tid] + wsum[2][tid] + wsum[3][tid];
    __syncthreads();

    if (tid < 200) {
      int r = tid / 20, j = tid % 20;
      double v;
      if (j < 10) {
        int a = r < j ? r : j;
        int b = r < j ? j : r;
        int q = 10 * a - a * (a - 1) / 2 + (b - a);
        v = xtx_sh[q];
      } else {
        v = (j - 10 == r) ? 1.0 : 0.0;
      }
      A[r][j] = v;
    }
    __syncthreads();
    int r_ = tid / 20, j_ = tid % 20;
    bool in200 = (tid < 200);
    for (int c = 0; c < 10; ++c) {
      if (tid == 0) {
        int piv = c; double best = fabs(A[c][c]);
        for (int r2 = c + 1; r2 < 10; ++r2)
          if (fabs(A[r2][c]) > best) { best = fabs(A[r2][c]); piv = r2; }
        piv_sh = piv;
      }
      __syncthreads();
      int piv = piv_sh;
      if (piv != c && tid < 20) {
        double t = A[c][tid]; A[c][tid] = A[piv][tid]; A[piv][tid] = t;
      }
      __syncthreads();
      if (tid == 0) pv_sh = A[c][c];
      __syncthreads();
      if (tid < 20) A[c][tid] *= (1.0 / pv_sh);
      __syncthreads();
      double f = 0.0, acj = 0.0;
      bool act = in200 && (r_ != c);
      if (act) { f = A[r_][c]; acj = A[c][j_]; }
      __syncthreads();
      if (act) A[r_][j_] -= f * acj;
      __syncthreads();
    }
    if (tid < 100) Mi[tid] = A[tid / 10][10 + (tid % 10)];
  } else if (blockIdx.x == 1) {
    __shared__ float redf[256];
    float m = 1e30f;
    for (int i = tid; i < L_VAR; i += 256) m = fminf(m, obs_p[i]);
    redf[tid] = m; __syncthreads();
    for (int off = 128; off > 0; off >>= 1) {
      if (tid < off) redf[tid] = fminf(redf[tid], redf[tid + off]);
      __syncthreads();
    }
    if (tid == 0) *minp = redf[0];
  } else if (blockIdx.x == 2) {
    for (int idx = tid; idx < 10 * N_SAMP; idx += 256) {
      int k = idx / N_SAMP, i = idx - k * N_SAMP;
      Xt[idx] = X[i * 10 + k];
    }
  } else {
    // blocks 3..58: zero bf16 Yt pad rows 200..255 (big path only)
    if (yhi) {
      int row = R_PERM + (blockIdx.x - 3);
      size_t base = (size_t)row * KPAD;
      for (int i = tid; i < KPAD; i += 256) {
        yhi[base + i] = 0;
        ylo[base + i] = 0;
      }
    }
  }
}

// ================= K2 (fallback): XtG/GG partials + key chain =================
__global__ __launch_bounds__(256) void k2_xtg(
    const float* __restrict__ G, const float* __restrict__ X,
    const int* __restrict__ seedp, float* __restrict__ XtGp,
    float* __restrict__ GGp, unsigned* __restrict__ pkeys) {
  if (blockIdx.x == 40) {
    if (blockIdx.y == 0 && threadIdx.x == 0) gen_pkeys(seedp, pkeys);
    return;
  }
  int l = blockIdx.x * 256 + threadIdx.x;
  bool valid = (l < L_VAR);
  int i0 = blockIdx.y * 400;
  float acc[10];
  #pragma unroll
  for (int k = 0; k < 10; ++k) acc[k] = 0.f;
  float g2 = 0.f;
  for (int i = i0; i < i0 + 400; ++i) {
    float g = valid ? G[(size_t)i * L_VAR + l] : 0.f;
    #pragma unroll
    for (int k = 0; k < 10; ++k) acc[k] = fmaf(g, X[i * 10 + k], acc[k]);
    g2 = fmaf(g, g, g2);
  }
  if (valid) {
    int part = blockIdx.y;
    #pragma unroll
    for (int k = 0; k < 10; ++k)
      XtGp[((size_t)part * 10 + k) * L_VAR + l] = acc[k];
    GGp[(size_t)part * L_VAR + l] = g2;
  }
}

// ===== K2T (big): G pass -> G^T bf16 hi/lo + XtG/GG partials + key chain =====
__global__ __launch_bounds__(256) void k2t_pass(
    const float* __restrict__ G, const float* __restrict__ X,
    const int* __restrict__ seedp,
    unsigned short* __restrict__ GTHI, unsigned short* __restrict__ GTLO,
    float* __restrict__ XtGp2, float* __restrict__ GGp2,
    unsigned* __restrict__ pkeys) {
  if (blockIdx.x == 157) {
    // 2-lane parallel key chain: lane 0 computes next-key, lane 1 computes perm-key
    if (blockIdx.y == 0 && threadIdx.x < 2) {
      int t = threadIdx.x;
      uint32_t khi = 0u, klo = (uint32_t)(*seedp);
#if JAX_THREEFRY_PARTITIONABLE
      for (int r = 0; r < R_PERM; ++r) {
        uint2 res = tf2(khi, klo, 0u, (uint32_t)t);   // t=0 -> nk, t=1 -> pk
        if (t == 1) { pkeys[2 * r] = res.x; pkeys[2 * r + 1] = res.y; }
        khi = __shfl(res.x, 0, 64);
        klo = __shfl(res.y, 0, 64);
      }
#else
      if (t == 0) gen_pkeys(seedp, pkeys);
#endif
    }
    return;
  }
  __shared__ float T[128][69];
  __shared__ float Xsh[128][10];
  int tid = threadIdx.x;
  int l0 = blockIdx.x * 64, i0 = blockIdx.y * 128;
  for (int it = 0; it < 8; ++it) {
    int fi = it * 256 + tid;
    int row = fi >> 4, c4 = (fi & 15) * 4;
    int i = i0 + row, l = l0 + c4;
    float4 v = make_float4(0.f, 0.f, 0.f, 0.f);
    if (i < N_SAMP && l + 3 < L_VAR) v = *(const float4*)(G + (size_t)i * L_VAR + l);
    T[row][c4 + 0] = v.x; T[row][c4 + 1] = v.y; T[row][c4 + 2] = v.z; T[row][c4 + 3] = v.w;
  }
  for (int q = 0; q < 5; ++q) {
    int idx = q * 256 + tid;
    if (idx < 1280) {
      int row = idx / 10, k = idx - row * 10;
      int i = i0 + row;
      Xsh[row][k] = (i < N_SAMP) ? X[i * 10 + k] : 0.f;
    }
  }
  __syncthreads();
  {
    int w = tid >> 6, lam = tid & 63;
    int half = lam >> 5, i4 = (lam & 31) * 4;
    for (int g = 0; g < 8; ++g) {
      int lloc = g * 8 + w * 2 + half;
      float fv[4];
      fv[0] = T[i4 + 0][lloc]; fv[1] = T[i4 + 1][lloc];
      fv[2] = T[i4 + 2][lloc]; fv[3] = T[i4 + 3][lloc];
      ushort4 hv, lv;
      bf16split(fv[0], hv.x, lv.x);
      bf16split(fv[1], hv.y, lv.y);
      bf16split(fv[2], hv.z, lv.z);
      bf16split(fv[3], hv.w, lv.w);
      size_t idx = (size_t)(l0 + lloc) * KPAD + i0 + i4;
      *(ushort4*)(GTHI + idx) = hv;
      *(ushort4*)(GTLO + idx) = lv;
    }
  }
  int lc = tid & 63, iq = tid >> 6;
  float accx[10];
  #pragma unroll
  for (int k = 0; k < 10; ++k) accx[k] = 0.f;
  float g2 = 0.f;
  for (int j = 0; j < 32; ++j) {
    int i = iq * 32 + j;
    float tv = T[i][lc];
    g2 = fmaf(tv, tv, g2);
    #pragma unroll
    for (int k = 0; k < 10; ++k) accx[k] = fmaf(tv, Xsh[i][k], accx[k]);
  }
  __syncthreads();
  float* scr = &T[0][0];
  #pragma unroll
  for (int k = 0; k < 10; ++k) scr[(iq * 64 + lc) * 10 + k] = accx[k];
  scr[2560 + iq * 64 + lc] = g2;
  __syncthreads();
  for (int idx = tid; idx < 640; idx += 256) {
    int l = idx / 10, k = idx - l * 10;
    float t = scr[(0 * 64 + l) * 10 + k] + scr[(1 * 64 + l) * 10 + k]
            + scr[(2 * 64 + l) * 10 + k] + scr[(3 * 64 + l) * 10 + k];
    XtGp2[((size_t)blockIdx.y * 10 + k) * LPAD + l0 + l] = t;
  }
  if (tid < 64) {
    float s4 = scr[2560 + tid] + scr[2560 + 64 + tid] + scr[2560 + 128 + tid] + scr[2560 + 192 + tid];
    GGp2[(size_t)blockIdx.y * LPAD + l0 + tid] = s4;
  }
}

// ================= K3 (fallback) ==============================================
__global__ __launch_bounds__(256) void k3_gg(
    const float* __restrict__ XtGp, const float* __restrict__ GGp,
    const double* __restrict__ Mi, float* __restrict__ gg) {
  int l = blockIdx.x * 256 + threadIdx.x;
  if (l >= L_VAR) return;
  double t[10]; double g2 = 0.0;
  #pragma unroll
  for (int k = 0; k < 10; ++k) t[k] = 0.0;
  for (int part = 0; part < 5; ++part) {
    #pragma unroll
    for (int k = 0; k < 10; ++k)
      t[k] += (double)XtGp[((size_t)part * 10 + k) * L_VAR + l];
    g2 += (double)GGp[(size_t)part * L_VAR + l];
  }
  double corr = 0.0;
  #pragma unroll
  for (int k = 0; k < 10; ++k) {
    double a = 0.0;
    #pragma unroll
    for (int j = 0; j < 10; ++j) a += Mi[k * 10 + j] * t[j];
    corr += a * t[k];
  }
  gg[l] = (float)(g2 - corr);
}

// ================= K3T (big): gg + rgg from 16 partials =======================
__global__ __launch_bounds__(256) void k3t_gg(
    const float* __restrict__ XtGp2, const float* __restrict__ GGp2,
    const double* __restrict__ Mi, float* __restrict__ gg, float* __restrict__ rgg) {
  int l = blockIdx.x * 256 + threadIdx.x;
  if (l >= LPAD) return;
  double t[10]; double g2 = 0.0;
  #pragma unroll
  for (int k = 0; k < 10; ++k) t[k] = 0.0;
  for (int part = 0; part < 16; ++part) {
    #pragma unroll
    for (int k = 0; k < 10; ++k)
      t[k] += (double)XtGp2[((size_t)part * 10 + k) * LPAD + l];
    g2 += (double)GGp2[(size_t)part * LPAD + l];
  }
  double corr = 0.0;
  #pragma unroll
  for (int k = 0; k < 10; ++k) {
    double a = 0.0;
    #pragma unroll
    for (int j = 0; j < 10; ++j) a += Mi[k * 10 + j] * t[j];
    corr += a * t[k];
  }
  double v = g2 - corr;
  if (l < L_VAR) {
    gg[l] = (float)v;
    rgg[l] = (v > 0.0) ? (float)(1.0 / v) : 0.f;
  } else {
    rgg[l] = 0.f;
  }
}

// ======= K4 (1024 thr): per-permutation shuffle + residualized Yt =============
// Round-7: register-resident bitonic. Thread (w,l) holds elements 128w+l and
// 128w+64+l of both key arrays. Strides <=32 -> __shfl_xor (no barrier);
// stride 64 -> in-thread slot swap; only strides >=128 go through LDS
// (10 passes total vs 66). Network identical to original bitonic2048.
#define CEX(v, s, up) { \
  unsigned long long o_ = __shfl_xor((v), (s), 64); \
  bool lower_ = ((lane & (s)) == 0); \
  bool mn_ = (lower_ == (up)); \
  unsigned long long lo_ = ((v) < o_) ? (v) : o_; \
  unsigned long long hi_ = ((v) < o_) ? o_ : (v); \
  (v) = mn_ ? lo_ : hi_; }

#define CEXP(v0, v1, up) { \
  unsigned long long lo_ = ((v0) < (v1)) ? (v0) : (v1); \
  unsigned long long hi_ = ((v0) < (v1)) ? (v1) : (v0); \
  (v0) = (up) ? lo_ : hi_; (v1) = (up) ? hi_ : lo_; }

__global__ __launch_bounds__(1024) void k4_perm(
    const float* __restrict__ y, const float* __restrict__ offs,
    const float* __restrict__ Xt, const unsigned* __restrict__ pkeys,
    const double* __restrict__ Mi, float* __restrict__ Yt,
    float* __restrict__ yty, unsigned* __restrict__ s,
    unsigned short* __restrict__ yhi, unsigned short* __restrict__ ylo) {
  __shared__ unsigned long long arrA[2048];   // sort 1 keys
  __shared__ unsigned long long arrB[2048];   // sort 2 keys
  __shared__ float yp[2000];
  __shared__ double redL[16][10];
  __shared__ double wf[10];
  __shared__ double red16[16];
  __shared__ double mvd[10];
  __shared__ unsigned ksh[4];
  const int NT = 1024;
  int r = blockIdx.x, tid = threadIdx.x;
  int wid = tid >> 6, lane = tid & 63;

  if (tid == 0) {
    uint32_t phi = pkeys[2 * r], plo = pkeys[2 * r + 1];
#if JAX_THREEFRY_PARTITIONABLE
    uint2 sub1 = tf2(phi, plo, 0u, 1u);
    uint2 key1 = tf2(phi, plo, 0u, 0u);
    uint2 sub2 = tf2(key1.x, key1.y, 0u, 1u);
#else
    uint2 a0k = tf2(phi, plo, 0u, 2u), a1k = tf2(phi, plo, 1u, 3u);
    uint2 key1 = make_uint2(a0k.x, a1k.x);
    uint2 sub1 = make_uint2(a0k.y, a1k.y);
    uint2 b0k = tf2(key1.x, key1.y, 0u, 2u), b1k = tf2(key1.x, key1.y, 1u, 3u);
    uint2 sub2 = make_uint2(b0k.y, b1k.y);
#endif
    ksh[0] = sub1.x; ksh[1] = sub1.y; ksh[2] = sub2.x; ksh[3] = sub2.y;
  }
  __syncthreads();
  uint32_t s1x = ksh[0], s1y = ksh[1], s2x = ksh[2], s2y = ksh[3];

  int e0 = 128 * wid + lane;     // always < 2000
  int e1 = e0 + 64;              // >= 2000 only for wid 15, lane >= 16
  unsigned long long a0 = keyfor(s1x, s1y, e0), a1 = keyfor(s1x, s1y, e1);
  unsigned long long b0 = keyfor(s2x, s2y, e0), b1 = keyfor(s2x, s2y, e1);

  // ---- sizes 2..32: strides <=16, both slots share up = ((lane&size)==0) ----
  #pragma unroll
  for (int size = 2; size <= 32; size <<= 1) {
    for (int st = size >> 1; st > 0; st >>= 1) {
      bool up = ((lane & size) == 0);
      CEX(a0, st, up); CEX(a1, st, up);
      CEX(b0, st, up); CEX(b1, st, up);
    }
  }
  // ---- size 64: slot0 ascending, slot1 descending ----
  #pragma unroll
  for (int st = 32; st > 0; st >>= 1) {
    CEX(a0, st, true);  CEX(b0, st, true);
    CEX(a1, st, false); CEX(b1, st, false);
  }
  // ---- size 128: stride 64 = in-thread slot swap, then 32..1 ----
  {
    bool up = ((wid & 1) == 0);
    CEXP(a0, a1, up); CEXP(b0, b1, up);
    #pragma unroll
    for (int st = 32; st > 0; st >>= 1) {
      CEX(a0, st, up); CEX(a1, st, up);
      CEX(b0, st, up); CEX(b1, st, up);
    }
  }
  // ---- sizes 256..2048: strides >=128 via LDS, then 64..1 in regs ----
  for (int size = 256; size <= 2048; size <<= 1) {
    arrA[e0] = a0; arrA[e1] = a1;
    arrB[e0] = b0; arrB[e1] = b1;
    __syncthreads();
    for (int st = size >> 1; st >= 128; st >>= 1) {
      int i = 2 * tid - (tid & (st - 1));
      int j = i + st;
      bool up2 = ((i & size) == 0);
      unsigned long long x0 = arrA[i], x1 = arrA[j];
      unsigned long long z0 = arrB[i], z1 = arrB[j];
      bool swA = up2 ? (x0 > x1) : (x0 < x1);
      bool swB = up2 ? (z0 > z1) : (z0 < z1);
      if (swA) { arrA[i] = x1; arrA[j] = x0; }
      if (swB) { arrB[i] = z1; arrB[j] = z0; }
      __syncthreads();
    }
    a0 = arrA[e0]; a1 = arrA[e1];
    b0 = arrB[e0]; b1 = arrB[e1];
    bool up = (((unsigned)(128 * wid) & (unsigned)size) == 0);
    CEXP(a0, a1, up); CEXP(b0, b1, up);
    #pragma unroll
    for (int st = 32; st > 0; st >>= 1) {
      CEX(a0, st, up); CEX(a1, st, up);
      CEX(b0, st, up); CEX(b1, st, up);
    }
  }

  // store sorted A for random access; B stays in registers
  arrA[e0] = a0; arrA[e1] = a1;
  __syncthreads();

  // compose permutations: fin = sortA_idx[ sortB_idx[i] ]
  {
    int s2i0 = (int)(b0 & 2047u);
    int fin0 = (int)(arrA[s2i0] & 2047u);
    yp[e0] = y[fin0] - offs[e0];
    if (e1 < N_SAMP) {
      int s2i1 = (int)(b1 & 2047u);
      int fin1 = (int)(arrA[s2i1] & 2047u);
      yp[e1] = y[fin1] - offs[e1];
    }
  }
  __syncthreads();

  // w = Xt * yp  (10 components, single-barrier reduce)
  double wloc[10];
  #pragma unroll
  for (int k = 0; k < 10; ++k) wloc[k] = 0.0;
  for (int i = tid; i < N_SAMP; i += NT) {
    double v = (double)yp[i];
    #pragma unroll
    for (int k = 0; k < 10; ++k) wloc[k] += (double)Xt[k * N_SAMP + i] * v;
  }
  #pragma unroll
  for (int k = 0; k < 10; ++k) {
    double v = wloc[k];
    #pragma unroll
    for (int off = 32; off > 0; off >>= 1) v += __shfl_xor(v, off, 64);
    if (lane == 0) redL[wid][k] = v;
  }
  __syncthreads();
  if (tid < 10) {
    double t = 0.0;
    for (int w2 = 0; w2 < 16; ++w2) t += redL[w2][tid];
    wf[tid] = t;
  }
  __syncthreads();
  if (tid < 10) {
    double m = 0.0;
    #pragma unroll
    for (int k = 0; k < 10; ++k) m += Mi[tid * 10 + k] * wf[k];
    mvd[tid] = m;
  }
  __syncthreads();

  // residualize + yty
  double acc = 0.0;
  for (int i = tid; i < N_SAMP; i += NT) {
    double d = (double)yp[i];
    #pragma unroll
    for (int k = 0; k < 10; ++k) d -= (double)Xt[k * N_SAMP + i] * mvd[k];
    float v = (float)d;
    if (Yt) Yt[(size_t)r * N_SAMP + i] = v;
    yp[i] = v;
    acc += (double)v * (double)v;
  }
  #pragma unroll
  for (int off = 32; off > 0; off >>= 1) acc += __shfl_xor(acc, off, 64);
  if (lane == 0) red16[wid] = acc;
  __syncthreads();
  if (tid == 0) {
    double tot = 0.0;
    for (int w2 = 0; w2 < 16; ++w2) tot += red16[w2];
    yty[r] = (float)tot;
    s[r] = 0u;
  }

  __syncthreads();
  if (yhi) {
    for (int i = tid; i < KPAD; i += NT) {
      float v = (i < N_SAMP) ? yp[i] : 0.f;
      unsigned short h, l;
      bf16split(v, h, l);
      yhi[(size_t)r * KPAD + i] = h;
      ylo[(size_t)r * KPAD + i] = l;
    }
  }
}

// ================= K5 (fallback): fp32 VALU GEMM ==============================
__global__ __launch_bounds__(256) void k5_gemm(
    const float* __restrict__ G, const float* __restrict__ Yt,
    const float* __restrict__ gg, unsigned* __restrict__ s) {
  __shared__ float As[16][64];
  __shared__ float Bs[16][68];
  int tid = threadIdx.x;
  int tx = tid & 15, ty = tid >> 4;
  int l0 = blockIdx.x * 64, r0 = blockIdx.y * 64;
  int a_row = tid >> 4;
  int a_col = (tid & 15) * 4;
  int b_row = tid >> 2;
  int b_col = (tid & 3) * 4;
  int gl = l0 + a_col;
  bool aval = (gl < L_VAR);
  int gr = r0 + b_row;
  bool bval = (gr < R_PERM);
  const float* gbase = G + (size_t)a_row * L_VAR + gl;
  const float* ybase = Yt + (size_t)gr * N_SAMP + b_col;

  float4 aR = aval ? *(const float4*)gbase : make_float4(0.f, 0.f, 0.f, 0.f);
  float4 bR = bval ? *(const float4*)ybase : make_float4(0.f, 0.f, 0.f, 0.f);

  float acc[4][4];
  #pragma unroll
  for (int u = 0; u < 4; ++u)
    #pragma unroll
    for (int v = 0; v < 4; ++v) acc[u][v] = 0.f;

  for (int i0 = 0; i0 < N_SAMP; i0 += 16) {
    *(float4*)&As[a_row][a_col] = aR;
    Bs[b_col + 0][b_row] = bR.x;
    Bs[b_col + 1][b_row] = bR.y;
    Bs[b_col + 2][b_row] = bR.z;
    Bs[b_col + 3][b_row] = bR.w;
    __syncthreads();
    int inext = i0 + 16;
    if (inext < N_SAMP) {
      aR = aval ? *(const float4*)(gbase + (size_t)inext * L_VAR) : make_float4(0.f, 0.f, 0.f, 0.f);
      bR = bval ? *(const float4*)(ybase + inext) : make_float4(0.f, 0.f, 0.f, 0.f);
    }
    #pragma unroll
    for (int k = 0; k < 16; ++k) {
      float4 av = *(const float4*)&As[k][tx * 4];
      float4 bv = *(const float4*)&Bs[k][ty * 4];
      float a4[4] = {av.x, av.y, av.z, av.w};
      float b4[4] = {bv.x, bv.y, bv.z, bv.w};
      #pragma unroll
      for (int u = 0; u < 4; ++u)
        #pragma unroll
        for (int v = 0; v < 4; ++v)
          acc[u][v] = fmaf(a4[u], b4[v], acc[u][v]);
    }
    __syncthreads();
  }
  #pragma unroll
  for (int v = 0; v < 4; ++v) {
    int rr = r0 + ty * 4 + v;
    float m = 0.f;
    #pragma unroll
    for (int u = 0; u < 4; ++u) {
      int ll = l0 + tx * 4 + u;
      if (ll < L_VAR) {
        float U = acc[u][v];
        float t = U * U / gg[ll];
        m = fmaxf(m, t);
      }
    }
    #pragma unroll
    for (int off = 8; off > 0; off >>= 1) m = fmaxf(m, __shfl_xor(m, off, 64));
    if (tx == 0 && rr < R_PERM) atomicMax(&s[rr], __float_as_uint(m));
  }
}

// ===== K5F (big): 3-deep pipelined bf16x3 MFMA GEMM (round-8 best config) =====
// + T5 s_setprio around MFMA cluster (counted-vmcnt phase-split schedule)
// + pair-co-XCD block swizzle: blocks sharing a GT l-tile get dispatch IDs
//   differing by the group size (same id%8 -> same XCD) so GT L2-fill halves.
__device__ __forceinline__ void k5f_stage(
    int w, int lane, int kb, int l0, int rbase,
    const unsigned short* __restrict__ GTHI, const unsigned short* __restrict__ GTLO,
    const unsigned short* __restrict__ YHI, const unsigned short* __restrict__ YLO,
    unsigned short* Ah, unsigned short* Al, unsigned short* Bh, unsigned short* Bl) {
  int sub = lane >> 2, kq = lane & 3;
  #pragma unroll
  for (int j = 0; j < 6; ++j) {
    int c = w * 6 + j;
    const unsigned short* src;
    unsigned short* dst;
    if (c < 4) {
      src = GTHI + (size_t)(l0 + c * 16 + sub) * KPAD + kb + kq * 8;
      dst = Ah + c * 512 + lane * 8;
    } else if (c < 8) {
      src = GTLO + (size_t)(l0 + (c - 4) * 16 + sub) * KPAD + kb + kq * 8;
      dst = Al + (c - 4) * 512 + lane * 8;
    } else if (c < 16) {
      src = YHI + (size_t)(rbase + (c - 8) * 16 + sub) * KPAD + kb + kq * 8;
      dst = Bh + (c - 8) * 512 + lane * 8;
    } else {
      src = YLO + (size_t)(rbase + (c - 16) * 16 + sub) * KPAD + kb + kq * 8;
      dst = Bl + (c - 16) * 512 + lane * 8;
    }
    __builtin_amdgcn_global_load_lds(
        (const __attribute__((address_space(1))) unsigned int*)(const void*)src,
        (__attribute__((address_space(3))) unsigned int*)(void*)dst, 16, 0, 0);
  }
}

__global__ __launch_bounds__(256) void k5f_mfma(
    const unsigned short* __restrict__ GTHI, const unsigned short* __restrict__ GTLO,
    const unsigned short* __restrict__ YHI, const unsigned short* __restrict__ YLO,
    const float* __restrict__ rgg, unsigned* __restrict__ s) {
  __shared__ unsigned short Ah[3][64 * 32];
  __shared__ unsigned short Al[3][64 * 32];
  __shared__ unsigned short Bh[3][128 * 32];
  __shared__ unsigned short Bl[3][128 * 32];
  int tid = threadIdx.x;
  int w = tid >> 6, lane = tid & 63;
  int row16 = lane & 15, quad = lane >> 4;
  // pair-co-XCD swizzle: invert id -> (pair p, rhalf). Groups of 16 dispatch
  // ids hold 8 pairs: ids base..base+gsz-1 are rh=0, base+gsz.. are rh=1,
  // so pair-mates differ by gsz (gsz==8 except last partial group).
  int gid = blockIdx.x;
  int grp = gid >> 4;
  int rem = gid - (grp << 4);
  int gsz = 157 - grp * 8; if (gsz > 8) gsz = 8;
  int rhalf = (rem >= gsz) ? 1 : 0;
  int ltile = grp * 8 + (rem - rhalf * gsz);
  int l0 = ltile * 64;
  int rbase = rhalf * 128;

  float4v acc[4][2];
  #pragma unroll
  for (int mt = 0; mt < 4; ++mt)
    #pragma unroll
    for (int nt = 0; nt < 2; ++nt)
      acc[mt][nt] = (float4v){0.f, 0.f, 0.f, 0.f};

  // prologue: fill the 3-deep pipeline (18 outstanding loads per wave)
  k5f_stage(w, lane, 0,  l0, rbase, GTHI, GTLO, YHI, YLO, Ah[0], Al[0], Bh[0], Bl[0]);
  k5f_stage(w, lane, 32, l0, rbase, GTHI, GTLO, YHI, YLO, Ah[1], Al[1], Bh[1], Bl[1]);
  k5f_stage(w, lane, 64, l0, rbase, GTHI, GTLO, YHI, YLO, Ah[2], Al[2], Bh[2], Bl[2]);

  #pragma unroll 1
  for (int step = 0; step < 64; ++step) {
    int cur = step % 3;
    // wait for THIS step's 6 per-wave loads (oldest); keep up to 12 in flight.
    if (step < 62) {
      asm volatile("s_waitcnt vmcnt(12)" ::: "memory");
    } else if (step == 62) {
      asm volatile("s_waitcnt vmcnt(6)" ::: "memory");
    } else {
      asm volatile("s_waitcnt vmcnt(0)" ::: "memory");
    }
    __builtin_amdgcn_s_barrier();   // all waves' step data now visible
    __builtin_amdgcn_sched_barrier(0);

    short8v ahf[4], alf[4], bhf[2], blf[2];
    #pragma unroll
    for (int mt = 0; mt < 4; ++mt) {
      int o = (mt * 16 + row16) * 32 + quad * 8;
      ahf[mt] = *(const short8v*)&Ah[cur][o];
      alf[mt] = *(const short8v*)&Al[cur][o];
    }
    #pragma unroll
    for (int nt = 0; nt < 2; ++nt) {
      int o = (w * 32 + nt * 16 + row16) * 32 + quad * 8;
      bhf[nt] = *(const short8v*)&Bh[cur][o];
      blf[nt] = *(const short8v*)&Bl[cur][o];
    }
    __builtin_amdgcn_s_setprio(1);   // T5: favor MFMA-entering wave
    #pragma unroll
    for (int nt = 0; nt < 2; ++nt) {
      #pragma unroll
      for (int mt = 0; mt < 4; ++mt) {
        acc[mt][nt] = __builtin_amdgcn_mfma_f32_16x16x32_bf16(ahf[mt], bhf[nt], acc[mt][nt], 0, 0, 0);
        acc[mt][nt] = __builtin_amdgcn_mfma_f32_16x16x32_bf16(ahf[mt], blf[nt], acc[mt][nt], 0, 0, 0);
        acc[mt][nt] = __builtin_amdgcn_mfma_f32_16x16x32_bf16(alf[mt], bhf[nt], acc[mt][nt], 0, 0, 0);
      }
    }
    __builtin_amdgcn_s_setprio(0);
    // all waves done READING buf[cur] (ds_reads complete before their MFMAs);
    // then refill buf[cur] with step+3.
    __builtin_amdgcn_s_barrier();
    if (step + 3 < 64)
      k5f_stage(w, lane, (step + 3) * 32, l0, rbase, GTHI, GTLO, YHI, YLO,
                Ah[cur], Al[cur], Bh[cur], Bl[cur]);
  }

  // epilogue: wave owns 64l x 32r at (l0, rbase + w*32)
  float rl_[4][4];
  #pragma unroll
  for (int mt = 0; mt < 4; ++mt)
    #pragma unroll
    for (int q = 0; q < 4; ++q)
      rl_[mt][q] = rgg[l0 + mt * 16 + quad * 4 + q];
  #pragma unroll
  for (int nt = 0; nt < 2; ++nt) {
    float m = 0.f;
    #pragma unroll
    for (int mt = 0; mt < 4; ++mt)
      #pragma unroll
      for (int q = 0; q < 4; ++q) {
        float U = acc[mt][nt][q];
        m = fmaxf(m, U * U * rl_[mt][q]);
      }
    m = fmaxf(m, __shfl_xor(m, 16, 64));
    m = fmaxf(m, __shfl_xor(m, 32, 64));
    int r = rbase + w * 32 + nt * 16 + row16;
    if (quad == 0 && r < R_PERM) atomicMax(&s[r], __float_as_uint(m));
  }
}

// ================= K6: TS^2 -> p -> MoM + lane-parallel Newton -> betainc =====
__global__ __launch_bounds__(256) void k6_final(
    const unsigned* __restrict__ sbits, const float* __restrict__ yty,
    const float* __restrict__ minp, float* __restrict__ out) {
  __shared__ double red[256];
  int tid = threadIdx.x;
  double p = 0.0, p2 = 0.0, lp = 0.0, l1p = 0.0;
  if (tid < R_PERM) {
    double t = (double)__uint_as_float(sbits[tid]);
    double Y = (double)yty[tid];
    double ts2 = DOF_D * t / (Y - t);
    double pp = erfc(sqrt(0.5 * ts2));
    p = pp; p2 = pp * pp; lp = log(pp); l1p = log1p(-pp);
  }
  double Sp  = breduce_add(p, red, tid);
  double Sp2 = breduce_add(p2, red, tid);
  double S1  = breduce_add(lp, red, tid);
  double S2  = breduce_add(l1p, red, tid);
  if (tid < 64) {
    const double nobs = (double)R_PERM;
    double mean = Sp / nobs;
    double var = Sp2 / nobs - mean * mean;
    double k = mean * (mean * (1.0 - mean) / var - 1.0);
    double n = k * (1.0 / mean - 1.0);
    double old_lik = 10000.0, diff = 1000.0;
    int iter = 0;
    int sel = tid % 3, grp = tid / 3;
    while (fabs(diff) > 1e-3 && iter <= 100) {
      double arg = (sel == 0) ? k : (sel == 1) ? n : (k + n);
      double v = 0.0;
      if (grp == 0) v = dg_trigamma(arg);
      else if (grp == 1) v = dg_tetragamma(arg);
      else if (grp == 2) v = dg_digamma(arg);
      double pg1k = __shfl(v, 0, 64), pg1n = __shfl(v, 1, 64), pg1kn = __shfl(v, 2, 64);
      double pg2k = __shfl(v, 3, 64), pg2n = __shfl(v, 4, 64), pg2kn = __shfl(v, 5, 64);
      double dgk  = __shfl(v, 6, 64), dgn  = __shfl(v, 7, 64), dgkn  = __shfl(v, 8, 64);
      double i_kn = -pg1kn, i_k = pg1k + i_kn, i_n = pg1n + i_kn;
      double A = -nobs * i_k, B = -nobs * i_kn, C = -nobs * i_n;
      double s0 = S1 - nobs * (dgk - dgkn);
      double s1 = S2 - nobs * (dgn - dgkn);
      double det = A * C - B * B;
      double d0 = (C * s0 - B * s1) / det;
      double d1 = (A * s1 - B * s0) / det;
      double i_kkn = pg1n * pg2kn;
      double g_k = -pg1n * pg2k + i_kkn + pg1kn * pg2k;
      double i_knn = i_kkn - pg1kn * pg2n;
      double i_nnk = pg1k * pg2kn;
      double i_nkk = i_nnk - pg1kn * pg2k;
      double g_n = -pg1k * pg2n + i_nnk + pg1kn * pg2n;
      double scale = -pg1k * pg1n + (pg1k + pg1n) * pg1kn;
      double f = 0.5 / scale;
      double adj0 = f * (g_k * d0 * d0 + 2.0 * i_kkn * d0 * d1 + i_knn * d1 * d1);
      double adj1 = f * (i_nkk * d0 * d0 + 2.0 * i_nnk * d0 * d1 + g_n * d1 * d1);
      double nk_ = k - d0 - 0.5 * adj0;
      double nn_ = n - d1 - 0.5 * adj1;
      double arg2 = (tid == 0) ? nk_ : (tid == 1) ? nn_ : (nk_ + nn_);
      double lg = (tid < 3) ? lgamma(arg2) : 0.0;
      double lgk = __shfl(lg, 0, 64), lgn = __shfl(lg, 1, 64), lgkn = __shfl(lg, 2, 64);
      double nl = (nk_ - 1.0) * S1 + (nn_ - 1.0) * S2 - nobs * (lgk + lgn - lgkn);
      diff = old_lik - nl;
      old_lik = nl; k = nk_; n = nn_; ++iter;
    }
    if (tid == 0) {
      double conv = (fabs(diff) < 1e-3 && iter <= 100) ? 1.0 : 0.0;
      double adj = betainc_d(k, n, (double)(*minp));
      out[0] = (float)adj;
      out[1] = (float)k;
      out[2] = (float)n;
      out[3] = (float)conv;
    }
  }
}

__global__ void k_err(float* out) {
  if (threadIdx.x < 4) out[threadIdx.x] = -12345.0f;
}

extern "C" void kernel_launch(void* const* d_in, const int* in_sizes, int n_in,
                              void* d_out, int out_size, void* d_ws, size_t ws_size,
                              hipStream_t stream) {
  const float* X     = (const float*)d_in[0];
  const float* y     = (const float*)d_in[1];
  const float* G     = (const float*)d_in[2];
  const float* obs_p = (const float*)d_in[3];
  const float* offs  = (const float*)d_in[4];
  const int*   seedp = (const int*)d_in[5];
  float* out = (float*)d_out;

  if (ws_size < WS_OLD) {
    k_err<<<1, 64, 0, stream>>>(out);
    return;
  }
  char* ws = (char*)d_ws;
  unsigned* pkeys = (unsigned*)(ws + OFF_PKEYS);
  double*   Mi    = (double*)(ws + OFF_MI);
  float*    minp  = (float*)(ws + OFF_MINP);
  float*    Xt    = (float*)(ws + OFF_XT);
  float*    XtGp  = (float*)(ws + OFF_XTGP);
  float*    GGp   = (float*)(ws + OFF_GGP);
  float*    gg    = (float*)(ws + OFF_GG);
  float*    yty   = (float*)(ws + OFF_YTY);
  unsigned* s     = (unsigned*)(ws + OFF_S);
  float*    Yt    = (float*)(ws + OFF_YT);

  bool big = (ws_size >= WS_BIG);
  float*          rgg   = big ? (float*)(ws + OFF_RGG) : nullptr;
  unsigned short* yhi   = big ? (unsigned short*)(ws + OFF_YHI) : nullptr;
  unsigned short* ylo   = big ? (unsigned short*)(ws + OFF_YLO) : nullptr;
  float*          XtGp2 = big ? (float*)(ws + OFF_XTGP2) : nullptr;
  float*          GGp2  = big ? (float*)(ws + OFF_GGP2) : nullptr;
  unsigned short* GTHI  = big ? (unsigned short*)(ws + OFF_GTHI) : nullptr;
  unsigned short* GTLO  = big ? (unsigned short*)(ws + OFF_GTLO) : nullptr;

  if (big) {
    k1_setup<<<3 + (RPAD - R_PERM), 256, 0, stream>>>(X, obs_p, Xt, Mi, minp, yhi, ylo);
    k2t_pass<<<dim3(158, 16), 256, 0, stream>>>(G, X, seedp, GTHI, GTLO, XtGp2, GGp2, pkeys);
    k3t_gg<<<40, 256, 0, stream>>>(XtGp2, GGp2, Mi, gg, rgg);
    // big path: skip fallback-Yt write (region overlaps YHI) -> pass nullptr
    k4_perm<<<R_PERM, 1024, 0, stream>>>(y, offs, Xt, pkeys, Mi, nullptr, yty, s, yhi, ylo);
    k5f_mfma<<<314, 256, 0, stream>>>(GTHI, GTLO, yhi, ylo, rgg, s);
  } else {
    k1_setup<<<3, 256, 0, stream>>>(X, obs_p, Xt, Mi, minp, nullptr, nullptr);
    k2_xtg<<<dim3(41, 5), 256, 0, stream>>>(G, X, seedp, XtGp, GGp, pkeys);
    k3_gg<<<40, 256, 0, stream>>>(XtGp, GGp, Mi, gg);
    k4_perm<<<R_PERM, 1024, 0, stream>>>(y, offs, Xt, pkeys, Mi, Yt, yty, s, nullptr, nullptr);
    k5_gemm<<<dim3(157, 4), 256, 0, stream>>>(G, Yt, gg, s);
  }
  k6_final<<<1, 256, 0, stream>>>(s, yty, minp, out);
}

// Round 11
// 294.481 us; speedup vs baseline: 1.2533x; 1.2533x over previous
//
#include <hip/hip_runtime.h>
#include <stdint.h>

// PRNG variant: 1 = jax_threefry_partitionable=True (JAX >= 0.4.36 default)
#ifndef JAX_THREEFRY_PARTITIONABLE
#define JAX_THREEFRY_PARTITIONABLE 1
#endif

#define N_SAMP 2000
#define L_VAR  10000
#define R_PERM 200
#define DOF_D  1989.0   // N - K - 1

#define KPAD   2048     // padded K (samples) for MFMA path
#define LPAD   10048    // padded L (157*64)
#define RPAD   256      // padded R

// ---------------- workspace layout (bytes) ----------------
#define OFF_PKEYS  0UL
#define OFF_MI     1664UL
#define OFF_MINP   2464UL
#define OFF_XT     2560UL
#define OFF_XTGP   82560UL     // fallback only
#define OFF_GGP    2082560UL   // fallback only
#define OFF_GG     2282560UL
#define OFF_YTY    2322560UL
#define OFF_S      2323392UL
#define OFF_YT     2324224UL   // fallback only (big path overlaps with YHI)
#define WS_OLD     3924224UL
#define OFF_GGP2   82560UL     // float[16][10048] = 643,072 (over fallback XTGP)
#define OFF_RGG    725632UL    // float[10048]
#define OFF_YHI    2324224UL   // u16[256][2048] = 1,048,576 (over fallback YT)
#define OFF_XTGP2  3924224UL   // float[16][10][10048] = 6,430,720
#define OFF_YLO    10354944UL  // u16[256][2048]
#define OFF_GTHI   11403520UL  // u16[10048][2048] = 41,156,608
#define OFF_GTLO   52560128UL  // u16[10048][2048] -> ends 93,716,736
#define WS_BIG     95186432UL  // known good

typedef __attribute__((ext_vector_type(8))) short short8v;   // 8 bf16
typedef __attribute__((ext_vector_type(4))) float float4v;   // MFMA acc

// ---------------- threefry2x32, JAX-exact ----------------
__device__ __forceinline__ uint32_t rotl32(uint32_t v, int d) {
  return (v << d) | (v >> (32 - d));
}
__device__ __forceinline__ uint2 tf2(uint32_t k0, uint32_t k1, uint32_t x0, uint32_t x1) {
  uint32_t ks2 = k0 ^ k1 ^ 0x1BD11BDAu;
  x0 += k0; x1 += k1;
#define TF4(a,b,c,d) \
  x0 += x1; x1 = rotl32(x1,a); x1 ^= x0; \
  x0 += x1; x1 = rotl32(x1,b); x1 ^= x0; \
  x0 += x1; x1 = rotl32(x1,c); x1 ^= x0; \
  x0 += x1; x1 = rotl32(x1,d); x1 ^= x0;
  TF4(13,15,26,6)  x0 += k1;  x1 += ks2 + 1u;
  TF4(17,29,16,24) x0 += ks2; x1 += k0 + 2u;
  TF4(13,15,26,6)  x0 += k0;  x1 += k1 + 3u;
  TF4(17,29,16,24) x0 += k1;  x1 += ks2 + 4u;
  TF4(13,15,26,6)  x0 += ks2; x1 += k0 + 5u;
#undef TF4
  return make_uint2(x0, x1);
}

// single-thread fallback key chain
__device__ __forceinline__ void gen_pkeys(const int* seedp, unsigned* pkeys) {
  uint32_t khi = 0u, klo = (uint32_t)(*seedp);
  for (int r = 0; r < R_PERM; ++r) {
#if JAX_THREEFRY_PARTITIONABLE
    uint2 pk = tf2(khi, klo, 0u, 1u);
    uint2 nk = tf2(khi, klo, 0u, 0u);
#else
    uint2 t0 = tf2(khi, klo, 0u, 2u);
    uint2 t1 = tf2(khi, klo, 1u, 3u);
    uint2 nk = make_uint2(t0.x, t1.x);
    uint2 pk = make_uint2(t0.y, t1.y);
#endif
    pkeys[2 * r] = pk.x; pkeys[2 * r + 1] = pk.y;
    khi = nk.x; klo = nk.y;
  }
}

// ---------------- block reduce (256 threads, for k6) ----------------
__device__ __forceinline__ double breduce_add(double v, double* red, int tid) {
  red[tid] = v; __syncthreads();
  for (int off = 128; off > 0; off >>= 1) {
    if (tid < off) red[tid] += red[tid + off];
    __syncthreads();
  }
  double r = red[0]; __syncthreads();
  return r;
}

// ---------------- special functions (double) ----------------
__device__ double dg_digamma(double x) {
  if (!(x > 0.0)) return __builtin_nan("");
  double r = 0.0;
  while (x < 8.0) { r -= 1.0 / x; x += 1.0; }
  double t = 1.0 / x, t2 = t * t;
  double ser = t2 * (1.0/12.0 - t2*(1.0/120.0 - t2*(1.0/252.0 - t2*(1.0/240.0 - t2*(1.0/132.0)))));
  return r + log(x) - 0.5 * t - ser;
}
__device__ double dg_trigamma(double x) {
  if (!(x > 0.0)) return __builtin_nan("");
  double r = 0.0;
  while (x < 8.0) { r += 1.0 / (x * x); x += 1.0; }
  double t = 1.0 / x, t2 = t * t;
  double P = 1.0/6.0 - t2*(1.0/30.0 - t2*(1.0/42.0 - t2*(1.0/30.0 - t2*(5.0/66.0))));
  return r + t + 0.5 * t2 + t * t2 * P;
}
__device__ double dg_tetragamma(double x) {
  if (!(x > 0.0)) return __builtin_nan("");
  double r = 0.0;
  while (x < 8.0) { r -= 2.0 / (x * x * x); x += 1.0; }
  double t = 1.0 / x, t2 = t * t;
  double Q = 1.0 + t + 0.5*t2 - t2*t2*(1.0/6.0 - t2*(1.0/6.0 - t2*(3.0/10.0)));
  return r - t2 * Q;
}
__device__ double betacf_d(double a, double b, double x) {
  const double FPMIN = 1e-300, EPS = 3e-16;
  double qab = a + b, qap = a + 1.0, qam = a - 1.0;
  double c = 1.0, d = 1.0 - qab * x / qap;
  if (fabs(d) < FPMIN) d = FPMIN;
  d = 1.0 / d; double h = d;
  for (int m = 1; m <= 300; ++m) {
    int m2 = 2 * m;
    double aa = m * (b - m) * x / ((qam + m2) * (a + m2));
    d = 1.0 + aa * d; if (fabs(d) < FPMIN) d = FPMIN;
    c = 1.0 + aa / c; if (fabs(c) < FPMIN) c = FPMIN;
    d = 1.0 / d; double del = d * c; h *= del;
    aa = -(a + m) * (qab + m) * x / ((a + m2) * (qap + m2));
    d = 1.0 + aa * d; if (fabs(d) < FPMIN) d = FPMIN;
    c = 1.0 + aa / c; if (fabs(c) < FPMIN) c = FPMIN;
    d = 1.0 / d; del = d * c; h *= del;
    if (fabs(del - 1.0) < EPS) break;
  }
  return h;
}
__device__ double betainc_d(double a, double b, double x) {
  if (!(x > 0.0)) return 0.0;
  if (x >= 1.0) return 1.0;
  double lnbt = lgamma(a + b) - lgamma(a) - lgamma(b) + a * log(x) + b * log1p(-x);
  double bt = exp(lnbt);
  if (x < (a + 1.0) / (a + b + 2.0)) return bt * betacf_d(a, b, x) / a;
  else return 1.0 - bt * betacf_d(b, a, 1.0 - x) / b;
}

__device__ __forceinline__ void tri_ab(int q, int& a, int& b) {
  int aa = 0, rem = q;
  while (rem >= 10 - aa) { rem -= 10 - aa; ++aa; }
  a = aa; b = aa + rem;
}

// split fp32 -> bf16 hi + bf16 lo (truncation split)
__device__ __forceinline__ void bf16split(float f, unsigned short& h, unsigned short& l) {
  unsigned u = __float_as_uint(f);
  h = (unsigned short)(u >> 16);
  float rem = f - __uint_as_float(u & 0xFFFF0000u);
  l = (unsigned short)(__float_as_uint(rem) >> 16);
}

// per-element sort key (matches original fill_keys exactly)
__device__ __forceinline__ unsigned long long keyfor(uint32_t kx, uint32_t ky, int e) {
  if (e >= N_SAMP) return ~0ull;
#if JAX_THREEFRY_PARTITIONABLE
  uint2 o = tf2(kx, ky, 0u, (uint32_t)e);
  uint32_t bits = o.x ^ o.y;
  return (((unsigned long long)bits) << 11) | (unsigned long long)e;
#else
  uint2 o = (e < 1000) ? tf2(kx, ky, (uint32_t)e, (uint32_t)(1000 + e))
                       : tf2(kx, ky, (uint32_t)(e - 1000), (uint32_t)e);
  uint32_t bits = (e < 1000) ? o.x : o.y;
  return (((unsigned long long)bits) << 11) | (unsigned long long)e;
#endif
}

// ---- shared k1 role body (used by standalone k1 and fused into k2t) ---------
__device__ void k1_role(
    int role, int tid,
    const float* __restrict__ X, const float* __restrict__ obs_p,
    float* __restrict__ Xt, double* __restrict__ Mi, float* __restrict__ minp,
    unsigned short* __restrict__ yhi, unsigned short* __restrict__ ylo) {
  if (role == 0) {
    __shared__ double wsum[4][55];
    __shared__ double xtx_sh[55];
    __shared__ double A[10][21];
    __shared__ int piv_sh;
    __shared__ double pv_sh;
    int wave = tid >> 6, lane = tid & 63;

    double acc[55];
    #pragma unroll
    for (int q = 0; q < 55; ++q) acc[q] = 0.0;
    for (int i = tid; i < N_SAMP; i += 256) {
      float xv[10];
      #pragma unroll
      for (int k = 0; k < 5; ++k) {
        float2 t2 = *(const float2*)(X + i * 10 + 2 * k);
        xv[2 * k] = t2.x; xv[2 * k + 1] = t2.y;
      }
      int q = 0;
      #pragma unroll
      for (int a = 0; a < 10; ++a)
        #pragma unroll
        for (int b = a; b < 10; ++b)
          acc[q++] += (double)xv[a] * (double)xv[b];
    }
    #pragma unroll
    for (int q = 0; q < 55; ++q) {
      double v = acc[q];
      #pragma unroll
      for (int off = 32; off > 0; off >>= 1) v += __shfl_xor(v, off, 64);
      if (lane == 0) wsum[wave][q] = v;
    }
    __syncthreads();
    if (tid < 55) xtx_sh[tid] = wsum[0][tid] + wsum[1][tid] + wsum[2][tid] + wsum[3][tid];
    __syncthreads();

    if (tid < 200) {
      int r = tid / 20, j = tid % 20;
      double v;
      if (j < 10) {
        int a = r < j ? r : j;
        int b = r < j ? j : r;
        int q = 10 * a - a * (a - 1) / 2 + (b - a);
        v = xtx_sh[q];
      } else {
        v = (j - 10 == r) ? 1.0 : 0.0;
      }
      A[r][j] = v;
    }
    __syncthreads();
    int r_ = tid / 20, j_ = tid % 20;
    bool in200 = (tid < 200);
    for (int c = 0; c < 10; ++c) {
      if (tid == 0) {
        int piv = c; double best = fabs(A[c][c]);
        for (int r2 = c + 1; r2 < 10; ++r2)
          if (fabs(A[r2][c]) > best) { best = fabs(A[r2][c]); piv = r2; }
        piv_sh = piv;
      }
      __syncthreads();
      int piv = piv_sh;
      if (piv != c && tid < 20) {
        double t = A[c][tid]; A[c][tid] = A[piv][tid]; A[piv][tid] = t;
      }
      __syncthreads();
      if (tid == 0) pv_sh = A[c][c];
      __syncthreads();
      if (tid < 20) A[c][tid] *= (1.0 / pv_sh);
      __syncthreads();
      double f = 0.0, acj = 0.0;
      bool act = in200 && (r_ != c);
      if (act) { f = A[r_][c]; acj = A[c][j_]; }
      __syncthreads();
      if (act) A[r_][j_] -= f * acj;
      __syncthreads();
    }
    if (tid < 100) Mi[tid] = A[tid / 10][10 + (tid % 10)];
  } else if (role == 1) {
    __shared__ float redf[256];
    float m = 1e30f;
    for (int i = tid; i < L_VAR; i += 256) m = fminf(m, obs_p[i]);
    redf[tid] = m; __syncthreads();
    for (int off = 128; off > 0; off >>= 1) {
      if (tid < off) redf[tid] = fminf(redf[tid], redf[tid + off]);
      __syncthreads();
    }
    if (tid == 0) *minp = redf[0];
  } else if (role == 2) {
    for (int idx = tid; idx < 10 * N_SAMP; idx += 256) {
      int k = idx / N_SAMP, i = idx - k * N_SAMP;
      Xt[idx] = X[i * 10 + k];
    }
  } else {
    // roles 3..58: zero bf16 Yt pad rows 200..255 (big path only)
    if (yhi) {
      int row = R_PERM + (role - 3);
      size_t base = (size_t)row * KPAD;
      for (int i = tid; i < KPAD; i += 256) {
        yhi[base + i] = 0;
        ylo[base + i] = 0;
      }
    }
  }
}

// ====== K1 (fallback path standalone) ========================================
__global__ __launch_bounds__(256) void k1_setup(
    const float* __restrict__ X, const float* __restrict__ obs_p,
    float* __restrict__ Xt, double* __restrict__ Mi, float* __restrict__ minp,
    unsigned short* __restrict__ yhi, unsigned short* __restrict__ ylo) {
  k1_role((int)blockIdx.x, (int)threadIdx.x, X, obs_p, Xt, Mi, minp, yhi, ylo);
}

// ================= K2 (fallback): XtG/GG partials + key chain =================
__global__ __launch_bounds__(256) void k2_xtg(
    const float* __restrict__ G, const float* __restrict__ X,
    const int* __restrict__ seedp, float* __restrict__ XtGp,
    float* __restrict__ GGp, unsigned* __restrict__ pkeys) {
  if (blockIdx.x == 40) {
    if (blockIdx.y == 0 && threadIdx.x == 0) gen_pkeys(seedp, pkeys);
    return;
  }
  int l = blockIdx.x * 256 + threadIdx.x;
  bool valid = (l < L_VAR);
  int i0 = blockIdx.y * 400;
  float acc[10];
  #pragma unroll
  for (int k = 0; k < 10; ++k) acc[k] = 0.f;
  float g2 = 0.f;
  for (int i = i0; i < i0 + 400; ++i) {
    float g = valid ? G[(size_t)i * L_VAR + l] : 0.f;
    #pragma unroll
    for (int k = 0; k < 10; ++k) acc[k] = fmaf(g, X[i * 10 + k], acc[k]);
    g2 = fmaf(g, g, g2);
  }
  if (valid) {
    int part = blockIdx.y;
    #pragma unroll
    for (int k = 0; k < 10; ++k)
      XtGp[((size_t)part * 10 + k) * L_VAR + l] = acc[k];
    GGp[(size_t)part * L_VAR + l] = g2;
  }
}

// ===== K2T (big): G pass -> G^T bf16 hi/lo + XtG/GG partials + key chain =====
// Round-10b: k1's 59 blocks fused in at blockIdx.x in [158,217), y==0 only --
// overlaps k1's serial ~10-13us under k2t. Math of both parts unchanged.
__global__ __launch_bounds__(256) void k2t_pass(
    const float* __restrict__ G, const float* __restrict__ X,
    const float* __restrict__ obs_p, const int* __restrict__ seedp,
    unsigned short* __restrict__ GTHI, unsigned short* __restrict__ GTLO,
    float* __restrict__ XtGp2, float* __restrict__ GGp2,
    unsigned* __restrict__ pkeys,
    float* __restrict__ Xt, double* __restrict__ Mi, float* __restrict__ minp,
    unsigned short* __restrict__ yhi, unsigned short* __restrict__ ylo) {
  if (blockIdx.x >= 158) {
    if (blockIdx.y != 0) return;
    k1_role((int)blockIdx.x - 158, (int)threadIdx.x, X, obs_p, Xt, Mi, minp, yhi, ylo);
    return;
  }
  if (blockIdx.x == 157) {
    // 2-lane parallel key chain
    if (blockIdx.y == 0 && threadIdx.x < 2) {
      int t = threadIdx.x;
      uint32_t khi = 0u, klo = (uint32_t)(*seedp);
#if JAX_THREEFRY_PARTITIONABLE
      for (int r = 0; r < R_PERM; ++r) {
        uint2 res = tf2(khi, klo, 0u, (uint32_t)t);   // t=0 -> nk, t=1 -> pk
        if (t == 1) { pkeys[2 * r] = res.x; pkeys[2 * r + 1] = res.y; }
        khi = __shfl(res.x, 0, 64);
        klo = __shfl(res.y, 0, 64);
      }
#else
      if (t == 0) gen_pkeys(seedp, pkeys);
#endif
    }
    return;
  }
  __shared__ float T[128][69];
  __shared__ float Xsh[128][10];
  int tid = threadIdx.x;
  int l0 = blockIdx.x * 64, i0 = blockIdx.y * 128;
  for (int it = 0; it < 8; ++it) {
    int fi = it * 256 + tid;
    int row = fi >> 4, c4 = (fi & 15) * 4;
    int i = i0 + row, l = l0 + c4;
    float4 v = make_float4(0.f, 0.f, 0.f, 0.f);
    if (i < N_SAMP && l + 3 < L_VAR) v = *(const float4*)(G + (size_t)i * L_VAR + l);
    T[row][c4 + 0] = v.x; T[row][c4 + 1] = v.y; T[row][c4 + 2] = v.z; T[row][c4 + 3] = v.w;
  }
  for (int q = 0; q < 5; ++q) {
    int idx = q * 256 + tid;
    if (idx < 1280) {
      int row = idx / 10, k = idx - row * 10;
      int i = i0 + row;
      Xsh[row][k] = (i < N_SAMP) ? X[i * 10 + k] : 0.f;
    }
  }
  __syncthreads();
  {
    int w = tid >> 6, lam = tid & 63;
    int half = lam >> 5, i4 = (lam & 31) * 4;
    for (int g = 0; g < 8; ++g) {
      int lloc = g * 8 + w * 2 + half;
      float fv[4];
      fv[0] = T[i4 + 0][lloc]; fv[1] = T[i4 + 1][lloc];
      fv[2] = T[i4 + 2][lloc]; fv[3] = T[i4 + 3][lloc];
      ushort4 hv, lv;
      bf16split(fv[0], hv.x, lv.x);
      bf16split(fv[1], hv.y, lv.y);
      bf16split(fv[2], hv.z, lv.z);
      bf16split(fv[3], hv.w, lv.w);
      size_t idx = (size_t)(l0 + lloc) * KPAD + i0 + i4;
      *(ushort4*)(GTHI + idx) = hv;
      *(ushort4*)(GTLO + idx) = lv;
    }
  }
  int lc = tid & 63, iq = tid >> 6;
  float accx[10];
  #pragma unroll
  for (int k = 0; k < 10; ++k) accx[k] = 0.f;
  float g2 = 0.f;
  for (int j = 0; j < 32; ++j) {
    int i = iq * 32 + j;
    float tv = T[i][lc];
    g2 = fmaf(tv, tv, g2);
    #pragma unroll
    for (int k = 0; k < 10; ++k) accx[k] = fmaf(tv, Xsh[i][k], accx[k]);
  }
  __syncthreads();
  float* scr = &T[0][0];
  #pragma unroll
  for (int k = 0; k < 10; ++k) scr[(iq * 64 + lc) * 10 + k] = accx[k];
  scr[2560 + iq * 64 + lc] = g2;
  __syncthreads();
  for (int idx = tid; idx < 640; idx += 256) {
    int l = idx / 10, k = idx - l * 10;
    float t = scr[(0 * 64 + l) * 10 + k] + scr[(1 * 64 + l) * 10 + k]
            + scr[(2 * 64 + l) * 10 + k] + scr[(3 * 64 + l) * 10 + k];
    XtGp2[((size_t)blockIdx.y * 10 + k) * LPAD + l0 + l] = t;
  }
  if (tid < 64) {
    float s4 = scr[2560 + tid] + scr[2560 + 64 + tid] + scr[2560 + 128 + tid] + scr[2560 + 192 + tid];
    GGp2[(size_t)blockIdx.y * LPAD + l0 + tid] = s4;
  }
}

// ================= K3 (fallback) ==============================================
__global__ __launch_bounds__(256) void k3_gg(
    const float* __restrict__ XtGp, const float* __restrict__ GGp,
    const double* __restrict__ Mi, float* __restrict__ gg) {
  int l = blockIdx.x * 256 + threadIdx.x;
  if (l >= L_VAR) return;
  double t[10]; double g2 = 0.0;
  #pragma unroll
  for (int k = 0; k < 10; ++k) t[k] = 0.0;
  for (int part = 0; part < 5; ++part) {
    #pragma unroll
    for (int k = 0; k < 10; ++k)
      t[k] += (double)XtGp[((size_t)part * 10 + k) * L_VAR + l];
    g2 += (double)GGp[(size_t)part * L_VAR + l];
  }
  double corr = 0.0;
  #pragma unroll
  for (int k = 0; k < 10; ++k) {
    double a = 0.0;
    #pragma unroll
    for (int j = 0; j < 10; ++j) a += Mi[k * 10 + j] * t[j];
    corr += a * t[k];
  }
  gg[l] = (float)(g2 - corr);
}

// ================= K3T (big): gg + rgg from 16 partials =======================
__global__ __launch_bounds__(256) void k3t_gg(
    const float* __restrict__ XtGp2, const float* __restrict__ GGp2,
    const double* __restrict__ Mi, float* __restrict__ gg, float* __restrict__ rgg) {
  int l = blockIdx.x * 256 + threadIdx.x;
  if (l >= LPAD) return;
  double t[10]; double g2 = 0.0;
  #pragma unroll
  for (int k = 0; k < 10; ++k) t[k] = 0.0;
  for (int part = 0; part < 16; ++part) {
    #pragma unroll
    for (int k = 0; k < 10; ++k)
      t[k] += (double)XtGp2[((size_t)part * 10 + k) * LPAD + l];
    g2 += (double)GGp2[(size_t)part * LPAD + l];
  }
  double corr = 0.0;
  #pragma unroll
  for (int k = 0; k < 10; ++k) {
    double a = 0.0;
    #pragma unroll
    for (int j = 0; j < 10; ++j) a += Mi[k * 10 + j] * t[j];
    corr += a * t[k];
  }
  double v = g2 - corr;
  if (l < L_VAR) {
    gg[l] = (float)v;
    rgg[l] = (v > 0.0) ? (float)(1.0 / v) : 0.f;
  } else {
    rgg[l] = 0.f;
  }
}

// ======= K4 (1024 thr): per-permutation shuffle + residualized Yt =============
// Register-resident bitonic: strides <=32 via __shfl_xor, 64 in-thread,
// >=128 via LDS (10 passes). Network identical to original bitonic2048.
#define CEX(v, s, up) { \
  unsigned long long o_ = __shfl_xor((v), (s), 64); \
  bool lower_ = ((lane & (s)) == 0); \
  bool mn_ = (lower_ == (up)); \
  unsigned long long lo_ = ((v) < o_) ? (v) : o_; \
  unsigned long long hi_ = ((v) < o_) ? o_ : (v); \
  (v) = mn_ ? lo_ : hi_; }

#define CEXP(v0, v1, up) { \
  unsigned long long lo_ = ((v0) < (v1)) ? (v0) : (v1); \
  unsigned long long hi_ = ((v0) < (v1)) ? (v1) : (v0); \
  (v0) = (up) ? lo_ : hi_; (v1) = (up) ? hi_ : lo_; }

__global__ __launch_bounds__(1024) void k4_perm(
    const float* __restrict__ y, const float* __restrict__ offs,
    const float* __restrict__ Xt, const unsigned* __restrict__ pkeys,
    const double* __restrict__ Mi, float* __restrict__ Yt,
    float* __restrict__ yty, unsigned* __restrict__ s,
    unsigned short* __restrict__ yhi, unsigned short* __restrict__ ylo) {
  __shared__ unsigned long long arrA[2048];   // sort 1 keys
  __shared__ unsigned long long arrB[2048];   // sort 2 keys
  __shared__ float yp[2000];
  __shared__ double redL[16][10];
  __shared__ double wf[10];
  __shared__ double red16[16];
  __shared__ double mvd[10];
  __shared__ unsigned ksh[4];
  const int NT = 1024;
  int r = blockIdx.x, tid = threadIdx.x;
  int wid = tid >> 6, lane = tid & 63;

  if (tid == 0) {
    uint32_t phi = pkeys[2 * r], plo = pkeys[2 * r + 1];
#if JAX_THREEFRY_PARTITIONABLE
    uint2 sub1 = tf2(phi, plo, 0u, 1u);
    uint2 key1 = tf2(phi, plo, 0u, 0u);
    uint2 sub2 = tf2(key1.x, key1.y, 0u, 1u);
#else
    uint2 a0k = tf2(phi, plo, 0u, 2u), a1k = tf2(phi, plo, 1u, 3u);
    uint2 key1 = make_uint2(a0k.x, a1k.x);
    uint2 sub1 = make_uint2(a0k.y, a1k.y);
    uint2 b0k = tf2(key1.x, key1.y, 0u, 2u), b1k = tf2(key1.x, key1.y, 1u, 3u);
    uint2 sub2 = make_uint2(b0k.y, b1k.y);
#endif
    ksh[0] = sub1.x; ksh[1] = sub1.y; ksh[2] = sub2.x; ksh[3] = sub2.y;
  }
  __syncthreads();
  uint32_t s1x = ksh[0], s1y = ksh[1], s2x = ksh[2], s2y = ksh[3];

  int e0 = 128 * wid + lane;     // always < 2000
  int e1 = e0 + 64;              // >= 2000 only for wid 15, lane >= 16
  unsigned long long a0 = keyfor(s1x, s1y, e0), a1 = keyfor(s1x, s1y, e1);
  unsigned long long b0 = keyfor(s2x, s2y, e0), b1 = keyfor(s2x, s2y, e1);

  // ---- sizes 2..32 ----
  #pragma unroll
  for (int size = 2; size <= 32; size <<= 1) {
    for (int st = size >> 1; st > 0; st >>= 1) {
      bool up = ((lane & size) == 0);
      CEX(a0, st, up); CEX(a1, st, up);
      CEX(b0, st, up); CEX(b1, st, up);
    }
  }
  // ---- size 64 ----
  #pragma unroll
  for (int st = 32; st > 0; st >>= 1) {
    CEX(a0, st, true);  CEX(b0, st, true);
    CEX(a1, st, false); CEX(b1, st, false);
  }
  // ---- size 128 ----
  {
    bool up = ((wid & 1) == 0);
    CEXP(a0, a1, up); CEXP(b0, b1, up);
    #pragma unroll
    for (int st = 32; st > 0; st >>= 1) {
      CEX(a0, st, up); CEX(a1, st, up);
      CEX(b0, st, up); CEX(b1, st, up);
    }
  }
  // ---- sizes 256..2048 ----
  for (int size = 256; size <= 2048; size <<= 1) {
    arrA[e0] = a0; arrA[e1] = a1;
    arrB[e0] = b0; arrB[e1] = b1;
    __syncthreads();
    for (int st = size >> 1; st >= 128; st >>= 1) {
      int i = 2 * tid - (tid & (st - 1));
      int j = i + st;
      bool up2 = ((i & size) == 0);
      unsigned long long x0 = arrA[i], x1 = arrA[j];
      unsigned long long z0 = arrB[i], z1 = arrB[j];
      bool swA = up2 ? (x0 > x1) : (x0 < x1);
      bool swB = up2 ? (z0 > z1) : (z0 < z1);
      if (swA) { arrA[i] = x1; arrA[j] = x0; }
      if (swB) { arrB[i] = z1; arrB[j] = z0; }
      __syncthreads();
    }
    a0 = arrA[e0]; a1 = arrA[e1];
    b0 = arrB[e0]; b1 = arrB[e1];
    bool up = (((unsigned)(128 * wid) & (unsigned)size) == 0);
    CEXP(a0, a1, up); CEXP(b0, b1, up);
    #pragma unroll
    for (int st = 32; st > 0; st >>= 1) {
      CEX(a0, st, up); CEX(a1, st, up);
      CEX(b0, st, up); CEX(b1, st, up);
    }
  }

  // store sorted A for random access; B stays in registers
  arrA[e0] = a0; arrA[e1] = a1;
  __syncthreads();

  // compose permutations: fin = sortA_idx[ sortB_idx[i] ]
  {
    int s2i0 = (int)(b0 & 2047u);
    int fin0 = (int)(arrA[s2i0] & 2047u);
    yp[e0] = y[fin0] - offs[e0];
    if (e1 < N_SAMP) {
      int s2i1 = (int)(b1 & 2047u);
      int fin1 = (int)(arrA[s2i1] & 2047u);
      yp[e1] = y[fin1] - offs[e1];
    }
  }
  __syncthreads();

  // w = Xt * yp  (10 components, single-barrier reduce)
  double wloc[10];
  #pragma unroll
  for (int k = 0; k < 10; ++k) wloc[k] = 0.0;
  for (int i = tid; i < N_SAMP; i += NT) {
    double v = (double)yp[i];
    #pragma unroll
    for (int k = 0; k < 10; ++k) wloc[k] += (double)Xt[k * N_SAMP + i] * v;
  }
  #pragma unroll
  for (int k = 0; k < 10; ++k) {
    double v = wloc[k];
    #pragma unroll
    for (int off = 32; off > 0; off >>= 1) v += __shfl_xor(v, off, 64);
    if (lane == 0) redL[wid][k] = v;
  }
  __syncthreads();
  if (tid < 10) {
    double t = 0.0;
    for (int w2 = 0; w2 < 16; ++w2) t += redL[w2][tid];
    wf[tid] = t;
  }
  __syncthreads();
  if (tid < 10) {
    double m = 0.0;
    #pragma unroll
    for (int k = 0; k < 10; ++k) m += Mi[tid * 10 + k] * wf[k];
    mvd[tid] = m;
  }
  __syncthreads();

  // residualize + yty
  double acc = 0.0;
  for (int i = tid; i < N_SAMP; i += NT) {
    double d = (double)yp[i];
    #pragma unroll
    for (int k = 0; k < 10; ++k) d -= (double)Xt[k * N_SAMP + i] * mvd[k];
    float v = (float)d;
    if (Yt) Yt[(size_t)r * N_SAMP + i] = v;
    yp[i] = v;
    acc += (double)v * (double)v;
  }
  #pragma unroll
  for (int off = 32; off > 0; off >>= 1) acc += __shfl_xor(acc, off, 64);
  if (lane == 0) red16[wid] = acc;
  __syncthreads();
  if (tid == 0) {
    double tot = 0.0;
    for (int w2 = 0; w2 < 16; ++w2) tot += red16[w2];
    yty[r] = (float)tot;
    s[r] = 0u;
  }

  __syncthreads();
  if (yhi) {
    for (int i = tid; i < KPAD; i += NT) {
      float v = (i < N_SAMP) ? yp[i] : 0.f;
      unsigned short h, l;
      bf16split(v, h, l);
      yhi[(size_t)r * KPAD + i] = h;
      ylo[(size_t)r * KPAD + i] = l;
    }
  }
}

// ================= K5 (fallback): fp32 VALU GEMM ==============================
__global__ __launch_bounds__(256) void k5_gemm(
    const float* __restrict__ G, const float* __restrict__ Yt,
    const float* __restrict__ gg, unsigned* __restrict__ s) {
  __shared__ float As[16][64];
  __shared__ float Bs[16][68];
  int tid = threadIdx.x;
  int tx = tid & 15, ty = tid >> 4;
  int l0 = blockIdx.x * 64, r0 = blockIdx.y * 64;
  int a_row = tid >> 4;
  int a_col = (tid & 15) * 4;
  int b_row = tid >> 2;
  int b_col = (tid & 3) * 4;
  int gl = l0 + a_col;
  bool aval = (gl < L_VAR);
  int gr = r0 + b_row;
  bool bval = (gr < R_PERM);
  const float* gbase = G + (size_t)a_row * L_VAR + gl;
  const float* ybase = Yt + (size_t)gr * N_SAMP + b_col;

  float4 aR = aval ? *(const float4*)gbase : make_float4(0.f, 0.f, 0.f, 0.f);
  float4 bR = bval ? *(const float4*)ybase : make_float4(0.f, 0.f, 0.f, 0.f);

  float acc[4][4];
  #pragma unroll
  for (int u = 0; u < 4; ++u)
    #pragma unroll
    for (int v = 0; v < 4; ++v) acc[u][v] = 0.f;

  for (int i0 = 0; i0 < N_SAMP; i0 += 16) {
    *(float4*)&As[a_row][a_col] = aR;
    Bs[b_col + 0][b_row] = bR.x;
    Bs[b_col + 1][b_row] = bR.y;
    Bs[b_col + 2][b_row] = bR.z;
    Bs[b_col + 3][b_row] = bR.w;
    __syncthreads();
    int inext = i0 + 16;
    if (inext < N_SAMP) {
      aR = aval ? *(const float4*)(gbase + (size_t)inext * L_VAR) : make_float4(0.f, 0.f, 0.f, 0.f);
      bR = bval ? *(const float4*)(ybase + inext) : make_float4(0.f, 0.f, 0.f, 0.f);
    }
    #pragma unroll
    for (int k = 0; k < 16; ++k) {
      float4 av = *(const float4*)&As[k][tx * 4];
      float4 bv = *(const float4*)&Bs[k][ty * 4];
      float a4[4] = {av.x, av.y, av.z, av.w};
      float b4[4] = {bv.x, bv.y, bv.z, bv.w};
      #pragma unroll
      for (int u = 0; u < 4; ++u)
        #pragma unroll
        for (int v = 0; v < 4; ++v)
          acc[u][v] = fmaf(a4[u], b4[v], acc[u][v]);
    }
    __syncthreads();
  }
  #pragma unroll
  for (int v = 0; v < 4; ++v) {
    int rr = r0 + ty * 4 + v;
    float m = 0.f;
    #pragma unroll
    for (int u = 0; u < 4; ++u) {
      int ll = l0 + tx * 4 + u;
      if (ll < L_VAR) {
        float U = acc[u][v];
        float t = U * U / gg[ll];
        m = fmaxf(m, t);
      }
    }
    #pragma unroll
    for (int off = 8; off > 0; off >>= 1) m = fmaxf(m, __shfl_xor(m, off, 64));
    if (tx == 0 && rr < R_PERM) atomicMax(&s[rr], __float_as_uint(m));
  }
}

// ===== K5F (big): 3-deep pipelined bf16x3 MFMA GEMM (round-8 best config) =====
// Tile 64l x 128r, grid 314, LDS 72 KB, triple-buffered, raw s_barrier +
// counted s_waitcnt vmcnt(12). No setprio / no swizzle (round-10 A/B: both
// net-negative; FETCH halved with no speedup -> schedule-bound, not mem-bound).
__device__ __forceinline__ void k5f_stage(
    int w, int lane, int kb, int l0, int rbase,
    const unsigned short* __restrict__ GTHI, const unsigned short* __restrict__ GTLO,
    const unsigned short* __restrict__ YHI, const unsigned short* __restrict__ YLO,
    unsigned short* Ah, unsigned short* Al, unsigned short* Bh, unsigned short* Bl) {
  int sub = lane >> 2, kq = lane & 3;
  #pragma unroll
  for (int j = 0; j < 6; ++j) {
    int c = w * 6 + j;
    const unsigned short* src;
    unsigned short* dst;
    if (c < 4) {
      src = GTHI + (size_t)(l0 + c * 16 + sub) * KPAD + kb + kq * 8;
      dst = Ah + c * 512 + lane * 8;
    } else if (c < 8) {
      src = GTLO + (size_t)(l0 + (c - 4) * 16 + sub) * KPAD + kb + kq * 8;
      dst = Al + (c - 4) * 512 + lane * 8;
    } else if (c < 16) {
      src = YHI + (size_t)(rbase + (c - 8) * 16 + sub) * KPAD + kb + kq * 8;
      dst = Bh + (c - 8) * 512 + lane * 8;
    } else {
      src = YLO + (size_t)(rbase + (c - 16) * 16 + sub) * KPAD + kb + kq * 8;
      dst = Bl + (c - 16) * 512 + lane * 8;
    }
    __builtin_amdgcn_global_load_lds(
        (const __attribute__((address_space(1))) unsigned int*)(const void*)src,
        (__attribute__((address_space(3))) unsigned int*)(void*)dst, 16, 0, 0);
  }
}

__global__ __launch_bounds__(256) void k5f_mfma(
    const unsigned short* __restrict__ GTHI, const unsigned short* __restrict__ GTLO,
    const unsigned short* __restrict__ YHI, const unsigned short* __restrict__ YLO,
    const float* __restrict__ rgg, unsigned* __restrict__ s) {
  __shared__ unsigned short Ah[3][64 * 32];
  __shared__ unsigned short Al[3][64 * 32];
  __shared__ unsigned short Bh[3][128 * 32];
  __shared__ unsigned short Bl[3][128 * 32];
  int tid = threadIdx.x;
  int w = tid >> 6, lane = tid & 63;
  int row16 = lane & 15, quad = lane >> 4;
  int ltile = blockIdx.x >> 1;
  int rhalf = blockIdx.x & 1;
  int l0 = ltile * 64;
  int rbase = rhalf * 128;

  float4v acc[4][2];
  #pragma unroll
  for (int mt = 0; mt < 4; ++mt)
    #pragma unroll
    for (int nt = 0; nt < 2; ++nt)
      acc[mt][nt] = (float4v){0.f, 0.f, 0.f, 0.f};

  // prologue: fill the 3-deep pipeline (18 outstanding loads per wave)
  k5f_stage(w, lane, 0,  l0, rbase, GTHI, GTLO, YHI, YLO, Ah[0], Al[0], Bh[0], Bl[0]);
  k5f_stage(w, lane, 32, l0, rbase, GTHI, GTLO, YHI, YLO, Ah[1], Al[1], Bh[1], Bl[1]);
  k5f_stage(w, lane, 64, l0, rbase, GTHI, GTLO, YHI, YLO, Ah[2], Al[2], Bh[2], Bl[2]);

  #pragma unroll 1
  for (int step = 0; step < 64; ++step) {
    int cur = step % 3;
    // wait for THIS step's 6 per-wave loads (oldest); keep up to 12 in flight.
    if (step < 62) {
      asm volatile("s_waitcnt vmcnt(12)" ::: "memory");
    } else if (step == 62) {
      asm volatile("s_waitcnt vmcnt(6)" ::: "memory");
    } else {
      asm volatile("s_waitcnt vmcnt(0)" ::: "memory");
    }
    __builtin_amdgcn_s_barrier();   // all waves' step data now visible
    __builtin_amdgcn_sched_barrier(0);

    short8v ahf[4], alf[4], bhf[2], blf[2];
    #pragma unroll
    for (int mt = 0; mt < 4; ++mt) {
      int o = (mt * 16 + row16) * 32 + quad * 8;
      ahf[mt] = *(const short8v*)&Ah[cur][o];
      alf[mt] = *(const short8v*)&Al[cur][o];
    }
    #pragma unroll
    for (int nt = 0; nt < 2; ++nt) {
      int o = (w * 32 + nt * 16 + row16) * 32 + quad * 8;
      bhf[nt] = *(const short8v*)&Bh[cur][o];
      blf[nt] = *(const short8v*)&Bl[cur][o];
    }
    #pragma unroll
    for (int nt = 0; nt < 2; ++nt) {
      #pragma unroll
      for (int mt = 0; mt < 4; ++mt) {
        acc[mt][nt] = __builtin_amdgcn_mfma_f32_16x16x32_bf16(ahf[mt], bhf[nt], acc[mt][nt], 0, 0, 0);
        acc[mt][nt] = __builtin_amdgcn_mfma_f32_16x16x32_bf16(ahf[mt], blf[nt], acc[mt][nt], 0, 0, 0);
        acc[mt][nt] = __builtin_amdgcn_mfma_f32_16x16x32_bf16(alf[mt], bhf[nt], acc[mt][nt], 0, 0, 0);
      }
    }
    // all waves done READING buf[cur]; refill it with step+3.
    __builtin_amdgcn_s_barrier();
    if (step + 3 < 64)
      k5f_stage(w, lane, (step + 3) * 32, l0, rbase, GTHI, GTLO, YHI, YLO,
                Ah[cur], Al[cur], Bh[cur], Bl[cur]);
  }

  // epilogue: wave owns 64l x 32r at (l0, rbase + w*32)
  float rl_[4][4];
  #pragma unroll
  for (int mt = 0; mt < 4; ++mt)
    #pragma unroll
    for (int q = 0; q < 4; ++q)
      rl_[mt][q] = rgg[l0 + mt * 16 + quad * 4 + q];
  #pragma unroll
  for (int nt = 0; nt < 2; ++nt) {
    float m = 0.f;
    #pragma unroll
    for (int mt = 0; mt < 4; ++mt)
      #pragma unroll
      for (int q = 0; q < 4; ++q) {
        float U = acc[mt][nt][q];
        m = fmaxf(m, U * U * rl_[mt][q]);
      }
    m = fmaxf(m, __shfl_xor(m, 16, 64));
    m = fmaxf(m, __shfl_xor(m, 32, 64));
    int r = rbase + w * 32 + nt * 16 + row16;
    if (quad == 0 && r < R_PERM) atomicMax(&s[r], __float_as_uint(m));
  }
}

// ================= K6: TS^2 -> p -> MoM + lane-parallel Newton -> betainc =====
__global__ __launch_bounds__(256) void k6_final(
    const unsigned* __restrict__ sbits, const float* __restrict__ yty,
    const float* __restrict__ minp, float* __restrict__ out) {
  __shared__ double red[256];
  int tid = threadIdx.x;
  double p = 0.0, p2 = 0.0, lp = 0.0, l1p = 0.0;
  if (tid < R_PERM) {
    double t = (double)__uint_as_float(sbits[tid]);
    double Y = (double)yty[tid];
    double ts2 = DOF_D * t / (Y - t);
    double pp = erfc(sqrt(0.5 * ts2));
    p = pp; p2 = pp * pp; lp = log(pp); l1p = log1p(-pp);
  }
  double Sp  = breduce_add(p, red, tid);
  double Sp2 = breduce_add(p2, red, tid);
  double S1  = breduce_add(lp, red, tid);
  double S2  = breduce_add(l1p, red, tid);
  if (tid < 64) {
    const double nobs = (double)R_PERM;
    double mean = Sp / nobs;
    double var = Sp2 / nobs - mean * mean;
    double k = mean * (mean * (1.0 - mean) / var - 1.0);
    double n = k * (1.0 / mean - 1.0);
    double old_lik = 10000.0, diff = 1000.0;
    int iter = 0;
    int sel = tid % 3, grp = tid / 3;
    while (fabs(diff) > 1e-3 && iter <= 100) {
      double arg = (sel == 0) ? k : (sel == 1) ? n : (k + n);
      double v = 0.0;
      if (grp == 0) v = dg_trigamma(arg);
      else if (grp == 1) v = dg_tetragamma(arg);
      else if (grp == 2) v = dg_digamma(arg);
      double pg1k = __shfl(v, 0, 64), pg1n = __shfl(v, 1, 64), pg1kn = __shfl(v, 2, 64);
      double pg2k = __shfl(v, 3, 64), pg2n = __shfl(v, 4, 64), pg2kn = __shfl(v, 5, 64);
      double dgk  = __shfl(v, 6, 64), dgn  = __shfl(v, 7, 64), dgkn  = __shfl(v, 8, 64);
      double i_kn = -pg1kn, i_k = pg1k + i_kn, i_n = pg1n + i_kn;
      double A = -nobs * i_k, B = -nobs * i_kn, C = -nobs * i_n;
      double s0 = S1 - nobs * (dgk - dgkn);
      double s1 = S2 - nobs * (dgn - dgkn);
      double det = A * C - B * B;
      double d0 = (C * s0 - B * s1) / det;
      double d1 = (A * s1 - B * s0) / det;
      double i_kkn = pg1n * pg2kn;
      double g_k = -pg1n * pg2k + i_kkn + pg1kn * pg2k;
      double i_knn = i_kkn - pg1kn * pg2n;
      double i_nnk = pg1k * pg2kn;
      double i_nkk = i_nnk - pg1kn * pg2k;
      double g_n = -pg1k * pg2n + i_nnk + pg1kn * pg2n;
      double scale = -pg1k * pg1n + (pg1k + pg1n) * pg1kn;
      double f = 0.5 / scale;
      double adj0 = f * (g_k * d0 * d0 + 2.0 * i_kkn * d0 * d1 + i_knn * d1 * d1);
      double adj1 = f * (i_nkk * d0 * d0 + 2.0 * i_nnk * d0 * d1 + g_n * d1 * d1);
      double nk_ = k - d0 - 0.5 * adj0;
      double nn_ = n - d1 - 0.5 * adj1;
      double arg2 = (tid == 0) ? nk_ : (tid == 1) ? nn_ : (nk_ + nn_);
      double lg = (tid < 3) ? lgamma(arg2) : 0.0;
      double lgk = __shfl(lg, 0, 64), lgn = __shfl(lg, 1, 64), lgkn = __shfl(lg, 2, 64);
      double nl = (nk_ - 1.0) * S1 + (nn_ - 1.0) * S2 - nobs * (lgk + lgn - lgkn);
      diff = old_lik - nl;
      old_lik = nl; k = nk_; n = nn_; ++iter;
    }
    if (tid == 0) {
      double conv = (fabs(diff) < 1e-3 && iter <= 100) ? 1.0 : 0.0;
      double adj = betainc_d(k, n, (double)(*minp));
      out[0] = (float)adj;
      out[1] = (float)k;
      out[2] = (float)n;
      out[3] = (float)conv;
    }
  }
}

__global__ void k_err(float* out) {
  if (threadIdx.x < 4) out[threadIdx.x] = -12345.0f;
}

extern "C" void kernel_launch(void* const* d_in, const int* in_sizes, int n_in,
                              void* d_out, int out_size, void* d_ws, size_t ws_size,
                              hipStream_t stream) {
  const float* X     = (const float*)d_in[0];
  const float* y     = (const float*)d_in[1];
  const float* G     = (const float*)d_in[2];
  const float* obs_p = (const float*)d_in[3];
  const float* offs  = (const float*)d_in[4];
  const int*   seedp = (const int*)d_in[5];
  float* out = (float*)d_out;

  if (ws_size < WS_OLD) {
    k_err<<<1, 64, 0, stream>>>(out);
    return;
  }
  char* ws = (char*)d_ws;
  unsigned* pkeys = (unsigned*)(ws + OFF_PKEYS);
  double*   Mi    = (double*)(ws + OFF_MI);
  float*    minp  = (float*)(ws + OFF_MINP);
  float*    Xt    = (float*)(ws + OFF_XT);
  float*    XtGp  = (float*)(ws + OFF_XTGP);
  float*    GGp   = (float*)(ws + OFF_GGP);
  float*    gg    = (float*)(ws + OFF_GG);
  float*    yty   = (float*)(ws + OFF_YTY);
  unsigned* s     = (unsigned*)(ws + OFF_S);
  float*    Yt    = (float*)(ws + OFF_YT);

  bool big = (ws_size >= WS_BIG);
  float*          rgg   = big ? (float*)(ws + OFF_RGG) : nullptr;
  unsigned short* yhi   = big ? (unsigned short*)(ws + OFF_YHI) : nullptr;
  unsigned short* ylo   = big ? (unsigned short*)(ws + OFF_YLO) : nullptr;
  float*          XtGp2 = big ? (float*)(ws + OFF_XTGP2) : nullptr;
  float*          GGp2  = big ? (float*)(ws + OFF_GGP2) : nullptr;
  unsigned short* GTHI  = big ? (unsigned short*)(ws + OFF_GTHI) : nullptr;
  unsigned short* GTLO  = big ? (unsigned short*)(ws + OFF_GTLO) : nullptr;

  if (big) {
    // k1's 59 role-blocks fused into k2t (x in [158,217), y==0) -> one launch
    k2t_pass<<<dim3(158 + 59, 16), 256, 0, stream>>>(
        G, X, obs_p, seedp, GTHI, GTLO, XtGp2, GGp2, pkeys,
        Xt, Mi, minp, yhi, ylo);
    k3t_gg<<<40, 256, 0, stream>>>(XtGp2, GGp2, Mi, gg, rgg);
    // big path: skip fallback-Yt write (region overlaps YHI) -> pass nullptr
    k4_perm<<<R_PERM, 1024, 0, stream>>>(y, offs, Xt, pkeys, Mi, nullptr, yty, s, yhi, ylo);
    k5f_mfma<<<314, 256, 0, stream>>>(GTHI, GTLO, yhi, ylo, rgg, s);
  } else {
    k1_setup<<<3, 256, 0, stream>>>(X, obs_p, Xt, Mi, minp, nullptr, nullptr);
    k2_xtg<<<dim3(41, 5), 256, 0, stream>>>(G, X, seedp, XtGp, GGp, pkeys);
    k3_gg<<<40, 256, 0, stream>>>(XtGp, GGp, Mi, gg);
    k4_perm<<<R_PERM, 1024, 0, stream>>>(y, offs, Xt, pkeys, Mi, Yt, yty, s, nullptr, nullptr);
    k5_gemm<<<dim3(157, 4), 256, 0, stream>>>(G, Yt, gg, s);
  }
  k6_final<<<1, 256, 0, stream>>>(s, yty, minp, out);
}

// Round 12
// 293.931 us; speedup vs baseline: 1.2557x; 1.0019x over previous
//
#include <hip/hip_runtime.h>
#include <stdint.h>

// PRNG variant: 1 = jax_threefry_partitionable=True (JAX >= 0.4.36 default)
#ifndef JAX_THREEFRY_PARTITIONABLE
#define JAX_THREEFRY_PARTITIONABLE 1
#endif

#define N_SAMP 2000
#define L_VAR  10000
#define R_PERM 200
#define DOF_D  1989.0   // N - K - 1

#define KPAD   2048     // padded K (samples) for MFMA path
#define LPAD   10048    // padded L (157*64)
#define RPAD   256      // padded R

// ---------------- workspace layout (bytes) ----------------
#define OFF_PKEYS  0UL
#define OFF_MI     1664UL
#define OFF_MINP   2464UL
#define OFF_XT     2560UL
#define OFF_XTGP   82560UL     // fallback only
#define OFF_GGP    2082560UL   // fallback only
#define OFF_GG     2282560UL
#define OFF_YTY    2322560UL
#define OFF_S      2323392UL
#define OFF_YT     2324224UL   // fallback only (big path overlaps with YHI)
#define WS_OLD     3924224UL
#define OFF_GGP2   82560UL     // float[16][10048] = 643,072 (over fallback XTGP)
#define OFF_RGG    725632UL    // float[10048] (unused since round-11b fold)
#define OFF_YHI    2324224UL   // u16[256][2048] = 1,048,576 (over fallback YT)
#define OFF_XTGP2  3924224UL   // float[16][10][10048] = 6,430,720
#define OFF_YLO    10354944UL  // u16[256][2048]
#define OFF_GTHI   11403520UL  // u16[10048][2048] = 41,156,608
#define OFF_GTLO   52560128UL  // u16[10048][2048] -> ends 93,716,736
#define WS_BIG     95186432UL  // known good

typedef __attribute__((ext_vector_type(8))) short short8v;   // 8 bf16
typedef __attribute__((ext_vector_type(4))) float float4v;   // MFMA acc

// ---------------- threefry2x32, JAX-exact ----------------
__device__ __forceinline__ uint32_t rotl32(uint32_t v, int d) {
  return (v << d) | (v >> (32 - d));
}
__device__ __forceinline__ uint2 tf2(uint32_t k0, uint32_t k1, uint32_t x0, uint32_t x1) {
  uint32_t ks2 = k0 ^ k1 ^ 0x1BD11BDAu;
  x0 += k0; x1 += k1;
#define TF4(a,b,c,d) \
  x0 += x1; x1 = rotl32(x1,a); x1 ^= x0; \
  x0 += x1; x1 = rotl32(x1,b); x1 ^= x0; \
  x0 += x1; x1 = rotl32(x1,c); x1 ^= x0; \
  x0 += x1; x1 = rotl32(x1,d); x1 ^= x0;
  TF4(13,15,26,6)  x0 += k1;  x1 += ks2 + 1u;
  TF4(17,29,16,24) x0 += ks2; x1 += k0 + 2u;
  TF4(13,15,26,6)  x0 += k0;  x1 += k1 + 3u;
  TF4(17,29,16,24) x0 += k1;  x1 += ks2 + 4u;
  TF4(13,15,26,6)  x0 += ks2; x1 += k0 + 5u;
#undef TF4
  return make_uint2(x0, x1);
}

// single-thread fallback key chain
__device__ __forceinline__ void gen_pkeys(const int* seedp, unsigned* pkeys) {
  uint32_t khi = 0u, klo = (uint32_t)(*seedp);
  for (int r = 0; r < R_PERM; ++r) {
#if JAX_THREEFRY_PARTITIONABLE
    uint2 pk = tf2(khi, klo, 0u, 1u);
    uint2 nk = tf2(khi, klo, 0u, 0u);
#else
    uint2 t0 = tf2(khi, klo, 0u, 2u);
    uint2 t1 = tf2(khi, klo, 1u, 3u);
    uint2 nk = make_uint2(t0.x, t1.x);
    uint2 pk = make_uint2(t0.y, t1.y);
#endif
    pkeys[2 * r] = pk.x; pkeys[2 * r + 1] = pk.y;
    khi = nk.x; klo = nk.y;
  }
}

// ---------------- block reduce (256 threads, for k6) ----------------
__device__ __forceinline__ double breduce_add(double v, double* red, int tid) {
  red[tid] = v; __syncthreads();
  for (int off = 128; off > 0; off >>= 1) {
    if (tid < off) red[tid] += red[tid + off];
    __syncthreads();
  }
  double r = red[0]; __syncthreads();
  return r;
}

// ---------------- special functions (double) ----------------
__device__ double dg_digamma(double x) {
  if (!(x > 0.0)) return __builtin_nan("");
  double r = 0.0;
  while (x < 8.0) { r -= 1.0 / x; x += 1.0; }
  double t = 1.0 / x, t2 = t * t;
  double ser = t2 * (1.0/12.0 - t2*(1.0/120.0 - t2*(1.0/252.0 - t2*(1.0/240.0 - t2*(1.0/132.0)))));
  return r + log(x) - 0.5 * t - ser;
}
__device__ double dg_trigamma(double x) {
  if (!(x > 0.0)) return __builtin_nan("");
  double r = 0.0;
  while (x < 8.0) { r += 1.0 / (x * x); x += 1.0; }
  double t = 1.0 / x, t2 = t * t;
  double P = 1.0/6.0 - t2*(1.0/30.0 - t2*(1.0/42.0 - t2*(1.0/30.0 - t2*(5.0/66.0))));
  return r + t + 0.5 * t2 + t * t2 * P;
}
__device__ double dg_tetragamma(double x) {
  if (!(x > 0.0)) return __builtin_nan("");
  double r = 0.0;
  while (x < 8.0) { r -= 2.0 / (x * x * x); x += 1.0; }
  double t = 1.0 / x, t2 = t * t;
  double Q = 1.0 + t + 0.5*t2 - t2*t2*(1.0/6.0 - t2*(1.0/6.0 - t2*(3.0/10.0)));
  return r - t2 * Q;
}
__device__ double betacf_d(double a, double b, double x) {
  const double FPMIN = 1e-300, EPS = 3e-16;
  double qab = a + b, qap = a + 1.0, qam = a - 1.0;
  double c = 1.0, d = 1.0 - qab * x / qap;
  if (fabs(d) < FPMIN) d = FPMIN;
  d = 1.0 / d; double h = d;
  for (int m = 1; m <= 300; ++m) {
    int m2 = 2 * m;
    double aa = m * (b - m) * x / ((qam + m2) * (a + m2));
    d = 1.0 + aa * d; if (fabs(d) < FPMIN) d = FPMIN;
    c = 1.0 + aa / c; if (fabs(c) < FPMIN) c = FPMIN;
    d = 1.0 / d; double del = d * c; h *= del;
    aa = -(a + m) * (qab + m) * x / ((a + m2) * (qap + m2));
    d = 1.0 + aa * d; if (fabs(d) < FPMIN) d = FPMIN;
    c = 1.0 + aa / c; if (fabs(c) < FPMIN) c = FPMIN;
    d = 1.0 / d; del = d * c; h *= del;
    if (fabs(del - 1.0) < EPS) break;
  }
  return h;
}
__device__ double betainc_d(double a, double b, double x) {
  if (!(x > 0.0)) return 0.0;
  if (x >= 1.0) return 1.0;
  double lnbt = lgamma(a + b) - lgamma(a) - lgamma(b) + a * log(x) + b * log1p(-x);
  double bt = exp(lnbt);
  if (x < (a + 1.0) / (a + b + 2.0)) return bt * betacf_d(a, b, x) / a;
  else return 1.0 - bt * betacf_d(b, a, 1.0 - x) / b;
}

__device__ __forceinline__ void tri_ab(int q, int& a, int& b) {
  int aa = 0, rem = q;
  while (rem >= 10 - aa) { rem -= 10 - aa; ++aa; }
  a = aa; b = aa + rem;
}

// split fp32 -> bf16 hi + bf16 lo (truncation split)
__device__ __forceinline__ void bf16split(float f, unsigned short& h, unsigned short& l) {
  unsigned u = __float_as_uint(f);
  h = (unsigned short)(u >> 16);
  float rem = f - __uint_as_float(u & 0xFFFF0000u);
  l = (unsigned short)(__float_as_uint(rem) >> 16);
}

// per-element sort key (matches original fill_keys exactly)
__device__ __forceinline__ unsigned long long keyfor(uint32_t kx, uint32_t ky, int e) {
  if (e >= N_SAMP) return ~0ull;
#if JAX_THREEFRY_PARTITIONABLE
  uint2 o = tf2(kx, ky, 0u, (uint32_t)e);
  uint32_t bits = o.x ^ o.y;
  return (((unsigned long long)bits) << 11) | (unsigned long long)e;
#else
  uint2 o = (e < 1000) ? tf2(kx, ky, (uint32_t)e, (uint32_t)(1000 + e))
                       : tf2(kx, ky, (uint32_t)(e - 1000), (uint32_t)e);
  uint32_t bits = (e < 1000) ? o.x : o.y;
  return (((unsigned long long)bits) << 11) | (unsigned long long)e;
#endif
}

// ---- shared k1 role body (used by standalone k1 and fused into k2t) ---------
__device__ void k1_role(
    int role, int tid,
    const float* __restrict__ X, const float* __restrict__ obs_p,
    float* __restrict__ Xt, double* __restrict__ Mi, float* __restrict__ minp,
    unsigned short* __restrict__ yhi, unsigned short* __restrict__ ylo) {
  if (role == 0) {
    __shared__ double wsum[4][55];
    __shared__ double xtx_sh[55];
    __shared__ double A[10][21];
    __shared__ int piv_sh;
    __shared__ double pv_sh;
    int wave = tid >> 6, lane = tid & 63;

    double acc[55];
    #pragma unroll
    for (int q = 0; q < 55; ++q) acc[q] = 0.0;
    for (int i = tid; i < N_SAMP; i += 256) {
      float xv[10];
      #pragma unroll
      for (int k = 0; k < 5; ++k) {
        float2 t2 = *(const float2*)(X + i * 10 + 2 * k);
        xv[2 * k] = t2.x; xv[2 * k + 1] = t2.y;
      }
      int q = 0;
      #pragma unroll
      for (int a = 0; a < 10; ++a)
        #pragma unroll
        for (int b = a; b < 10; ++b)
          acc[q++] += (double)xv[a] * (double)xv[b];
    }
    #pragma unroll
    for (int q = 0; q < 55; ++q) {
      double v = acc[q];
      #pragma unroll
      for (int off = 32; off > 0; off >>= 1) v += __shfl_xor(v, off, 64);
      if (lane == 0) wsum[wave][q] = v;
    }
    __syncthreads();
    if (tid < 55) xtx_sh[tid] = wsum[0][tid] + wsum[1][tid] + wsum[2][tid] + wsum[3][tid];
    __syncthreads();

    if (tid < 200) {
      int r = tid / 20, j = tid % 20;
      double v;
      if (j < 10) {
        int a = r < j ? r : j;
        int b = r < j ? j : r;
        int q = 10 * a - a * (a - 1) / 2 + (b - a);
        v = xtx_sh[q];
      } else {
        v = (j - 10 == r) ? 1.0 : 0.0;
      }
      A[r][j] = v;
    }
    __syncthreads();
    int r_ = tid / 20, j_ = tid % 20;
    bool in200 = (tid < 200);
    for (int c = 0; c < 10; ++c) {
      if (tid == 0) {
        int piv = c; double best = fabs(A[c][c]);
        for (int r2 = c + 1; r2 < 10; ++r2)
          if (fabs(A[r2][c]) > best) { best = fabs(A[r2][c]); piv = r2; }
        piv_sh = piv;
      }
      __syncthreads();
      int piv = piv_sh;
      if (piv != c && tid < 20) {
        double t = A[c][tid]; A[c][tid] = A[piv][tid]; A[piv][tid] = t;
      }
      __syncthreads();
      if (tid == 0) pv_sh = A[c][c];
      __syncthreads();
      if (tid < 20) A[c][tid] *= (1.0 / pv_sh);
      __syncthreads();
      double f = 0.0, acj = 0.0;
      bool act = in200 && (r_ != c);
      if (act) { f = A[r_][c]; acj = A[c][j_]; }
      __syncthreads();
      if (act) A[r_][j_] -= f * acj;
      __syncthreads();
    }
    if (tid < 100) Mi[tid] = A[tid / 10][10 + (tid % 10)];
  } else if (role == 1) {
    __shared__ float redf[256];
    float m = 1e30f;
    for (int i = tid; i < L_VAR; i += 256) m = fminf(m, obs_p[i]);
    redf[tid] = m; __syncthreads();
    for (int off = 128; off > 0; off >>= 1) {
      if (tid < off) redf[tid] = fminf(redf[tid], redf[tid + off]);
      __syncthreads();
    }
    if (tid == 0) *minp = redf[0];
  } else if (role == 2) {
    for (int idx = tid; idx < 10 * N_SAMP; idx += 256) {
      int k = idx / N_SAMP, i = idx - k * N_SAMP;
      Xt[idx] = X[i * 10 + k];
    }
  } else {
    // roles 3..58: zero bf16 Yt pad rows 200..255 (big path only)
    if (yhi) {
      int row = R_PERM + (role - 3);
      size_t base = (size_t)row * KPAD;
      for (int i = tid; i < KPAD; i += 256) {
        yhi[base + i] = 0;
        ylo[base + i] = 0;
      }
    }
  }
}

// ====== K1 (fallback path standalone) ========================================
__global__ __launch_bounds__(256) void k1_setup(
    const float* __restrict__ X, const float* __restrict__ obs_p,
    float* __restrict__ Xt, double* __restrict__ Mi, float* __restrict__ minp,
    unsigned short* __restrict__ yhi, unsigned short* __restrict__ ylo) {
  k1_role((int)blockIdx.x, (int)threadIdx.x, X, obs_p, Xt, Mi, minp, yhi, ylo);
}

// ================= K2 (fallback): XtG/GG partials + key chain =================
__global__ __launch_bounds__(256) void k2_xtg(
    const float* __restrict__ G, const float* __restrict__ X,
    const int* __restrict__ seedp, float* __restrict__ XtGp,
    float* __restrict__ GGp, unsigned* __restrict__ pkeys) {
  if (blockIdx.x == 40) {
    if (blockIdx.y == 0 && threadIdx.x == 0) gen_pkeys(seedp, pkeys);
    return;
  }
  int l = blockIdx.x * 256 + threadIdx.x;
  bool valid = (l < L_VAR);
  int i0 = blockIdx.y * 400;
  float acc[10];
  #pragma unroll
  for (int k = 0; k < 10; ++k) acc[k] = 0.f;
  float g2 = 0.f;
  for (int i = i0; i < i0 + 400; ++i) {
    float g = valid ? G[(size_t)i * L_VAR + l] : 0.f;
    #pragma unroll
    for (int k = 0; k < 10; ++k) acc[k] = fmaf(g, X[i * 10 + k], acc[k]);
    g2 = fmaf(g, g, g2);
  }
  if (valid) {
    int part = blockIdx.y;
    #pragma unroll
    for (int k = 0; k < 10; ++k)
      XtGp[((size_t)part * 10 + k) * L_VAR + l] = acc[k];
    GGp[(size_t)part * L_VAR + l] = g2;
  }
}

// ===== K2T (big): G pass -> G^T bf16 hi/lo + XtG/GG partials + key chain =====
// k1's 59 blocks fused in at blockIdx.x in [158,217), y==0 only.
__global__ __launch_bounds__(256) void k2t_pass(
    const float* __restrict__ G, const float* __restrict__ X,
    const float* __restrict__ obs_p, const int* __restrict__ seedp,
    unsigned short* __restrict__ GTHI, unsigned short* __restrict__ GTLO,
    float* __restrict__ XtGp2, float* __restrict__ GGp2,
    unsigned* __restrict__ pkeys,
    float* __restrict__ Xt, double* __restrict__ Mi, float* __restrict__ minp,
    unsigned short* __restrict__ yhi, unsigned short* __restrict__ ylo) {
  if (blockIdx.x >= 158) {
    if (blockIdx.y != 0) return;
    k1_role((int)blockIdx.x - 158, (int)threadIdx.x, X, obs_p, Xt, Mi, minp, yhi, ylo);
    return;
  }
  if (blockIdx.x == 157) {
    // 2-lane parallel key chain
    if (blockIdx.y == 0 && threadIdx.x < 2) {
      int t = threadIdx.x;
      uint32_t khi = 0u, klo = (uint32_t)(*seedp);
#if JAX_THREEFRY_PARTITIONABLE
      for (int r = 0; r < R_PERM; ++r) {
        uint2 res = tf2(khi, klo, 0u, (uint32_t)t);   // t=0 -> nk, t=1 -> pk
        if (t == 1) { pkeys[2 * r] = res.x; pkeys[2 * r + 1] = res.y; }
        khi = __shfl(res.x, 0, 64);
        klo = __shfl(res.y, 0, 64);
      }
#else
      if (t == 0) gen_pkeys(seedp, pkeys);
#endif
    }
    return;
  }
  __shared__ float T[128][69];
  __shared__ float Xsh[128][10];
  int tid = threadIdx.x;
  int l0 = blockIdx.x * 64, i0 = blockIdx.y * 128;
  for (int it = 0; it < 8; ++it) {
    int fi = it * 256 + tid;
    int row = fi >> 4, c4 = (fi & 15) * 4;
    int i = i0 + row, l = l0 + c4;
    float4 v = make_float4(0.f, 0.f, 0.f, 0.f);
    if (i < N_SAMP && l + 3 < L_VAR) v = *(const float4*)(G + (size_t)i * L_VAR + l);
    T[row][c4 + 0] = v.x; T[row][c4 + 1] = v.y; T[row][c4 + 2] = v.z; T[row][c4 + 3] = v.w;
  }
  for (int q = 0; q < 5; ++q) {
    int idx = q * 256 + tid;
    if (idx < 1280) {
      int row = idx / 10, k = idx - row * 10;
      int i = i0 + row;
      Xsh[row][k] = (i < N_SAMP) ? X[i * 10 + k] : 0.f;
    }
  }
  __syncthreads();
  {
    int w = tid >> 6, lam = tid & 63;
    int half = lam >> 5, i4 = (lam & 31) * 4;
    for (int g = 0; g < 8; ++g) {
      int lloc = g * 8 + w * 2 + half;
      float fv[4];
      fv[0] = T[i4 + 0][lloc]; fv[1] = T[i4 + 1][lloc];
      fv[2] = T[i4 + 2][lloc]; fv[3] = T[i4 + 3][lloc];
      ushort4 hv, lv;
      bf16split(fv[0], hv.x, lv.x);
      bf16split(fv[1], hv.y, lv.y);
      bf16split(fv[2], hv.z, lv.z);
      bf16split(fv[3], hv.w, lv.w);
      size_t idx = (size_t)(l0 + lloc) * KPAD + i0 + i4;
      *(ushort4*)(GTHI + idx) = hv;
      *(ushort4*)(GTLO + idx) = lv;
    }
  }
  int lc = tid & 63, iq = tid >> 6;
  float accx[10];
  #pragma unroll
  for (int k = 0; k < 10; ++k) accx[k] = 0.f;
  float g2 = 0.f;
  for (int j = 0; j < 32; ++j) {
    int i = iq * 32 + j;
    float tv = T[i][lc];
    g2 = fmaf(tv, tv, g2);
    #pragma unroll
    for (int k = 0; k < 10; ++k) accx[k] = fmaf(tv, Xsh[i][k], accx[k]);
  }
  __syncthreads();
  float* scr = &T[0][0];
  #pragma unroll
  for (int k = 0; k < 10; ++k) scr[(iq * 64 + lc) * 10 + k] = accx[k];
  scr[2560 + iq * 64 + lc] = g2;
  __syncthreads();
  for (int idx = tid; idx < 640; idx += 256) {
    int l = idx / 10, k = idx - l * 10;
    float t = scr[(0 * 64 + l) * 10 + k] + scr[(1 * 64 + l) * 10 + k]
            + scr[(2 * 64 + l) * 10 + k] + scr[(3 * 64 + l) * 10 + k];
    XtGp2[((size_t)blockIdx.y * 10 + k) * LPAD + l0 + l] = t;
  }
  if (tid < 64) {
    float s4 = scr[2560 + tid] + scr[2560 + 64 + tid] + scr[2560 + 128 + tid] + scr[2560 + 192 + tid];
    GGp2[(size_t)blockIdx.y * LPAD + l0 + tid] = s4;
  }
}

// ================= K3 (fallback) ==============================================
__global__ __launch_bounds__(256) void k3_gg(
    const float* __restrict__ XtGp, const float* __restrict__ GGp,
    const double* __restrict__ Mi, float* __restrict__ gg) {
  int l = blockIdx.x * 256 + threadIdx.x;
  if (l >= L_VAR) return;
  double t[10]; double g2 = 0.0;
  #pragma unroll
  for (int k = 0; k < 10; ++k) t[k] = 0.0;
  for (int part = 0; part < 5; ++part) {
    #pragma unroll
    for (int k = 0; k < 10; ++k)
      t[k] += (double)XtGp[((size_t)part * 10 + k) * L_VAR + l];
    g2 += (double)GGp[(size_t)part * L_VAR + l];
  }
  double corr = 0.0;
  #pragma unroll
  for (int k = 0; k < 10; ++k) {
    double a = 0.0;
    #pragma unroll
    for (int j = 0; j < 10; ++j) a += Mi[k * 10 + j] * t[j];
    corr += a * t[k];
  }
  gg[l] = (float)(g2 - corr);
}

// ======= K4 (1024 thr): per-permutation shuffle + residualized Yt =============
// Register-resident bitonic: strides <=32 via __shfl_xor, 64 in-thread,
// >=128 via LDS (10 passes). Network identical to original bitonic2048.
#define CEX(v, s, up) { \
  unsigned long long o_ = __shfl_xor((v), (s), 64); \
  bool lower_ = ((lane & (s)) == 0); \
  bool mn_ = (lower_ == (up)); \
  unsigned long long lo_ = ((v) < o_) ? (v) : o_; \
  unsigned long long hi_ = ((v) < o_) ? o_ : (v); \
  (v) = mn_ ? lo_ : hi_; }

#define CEXP(v0, v1, up) { \
  unsigned long long lo_ = ((v0) < (v1)) ? (v0) : (v1); \
  unsigned long long hi_ = ((v0) < (v1)) ? (v1) : (v0); \
  (v0) = (up) ? lo_ : hi_; (v1) = (up) ? hi_ : lo_; }

__global__ __launch_bounds__(1024) void k4_perm(
    const float* __restrict__ y, const float* __restrict__ offs,
    const float* __restrict__ Xt, const unsigned* __restrict__ pkeys,
    const double* __restrict__ Mi, float* __restrict__ Yt,
    float* __restrict__ yty, unsigned* __restrict__ s,
    unsigned short* __restrict__ yhi, unsigned short* __restrict__ ylo) {
  __shared__ unsigned long long arrA[2048];   // sort 1 keys
  __shared__ unsigned long long arrB[2048];   // sort 2 keys
  __shared__ float yp[2000];
  __shared__ double redL[16][10];
  __shared__ double wf[10];
  __shared__ double red16[16];
  __shared__ double mvd[10];
  __shared__ unsigned ksh[4];
  const int NT = 1024;
  int r = blockIdx.x, tid = threadIdx.x;
  int wid = tid >> 6, lane = tid & 63;

  if (tid == 0) {
    uint32_t phi = pkeys[2 * r], plo = pkeys[2 * r + 1];
#if JAX_THREEFRY_PARTITIONABLE
    uint2 sub1 = tf2(phi, plo, 0u, 1u);
    uint2 key1 = tf2(phi, plo, 0u, 0u);
    uint2 sub2 = tf2(key1.x, key1.y, 0u, 1u);
#else
    uint2 a0k = tf2(phi, plo, 0u, 2u), a1k = tf2(phi, plo, 1u, 3u);
    uint2 key1 = make_uint2(a0k.x, a1k.x);
    uint2 sub1 = make_uint2(a0k.y, a1k.y);
    uint2 b0k = tf2(key1.x, key1.y, 0u, 2u), b1k = tf2(key1.x, key1.y, 1u, 3u);
    uint2 sub2 = make_uint2(b0k.y, b1k.y);
#endif
    ksh[0] = sub1.x; ksh[1] = sub1.y; ksh[2] = sub2.x; ksh[3] = sub2.y;
  }
  __syncthreads();
  uint32_t s1x = ksh[0], s1y = ksh[1], s2x = ksh[2], s2y = ksh[3];

  int e0 = 128 * wid + lane;     // always < 2000
  int e1 = e0 + 64;              // >= 2000 only for wid 15, lane >= 16
  unsigned long long a0 = keyfor(s1x, s1y, e0), a1 = keyfor(s1x, s1y, e1);
  unsigned long long b0 = keyfor(s2x, s2y, e0), b1 = keyfor(s2x, s2y, e1);

  // ---- sizes 2..32 ----
  #pragma unroll
  for (int size = 2; size <= 32; size <<= 1) {
    for (int st = size >> 1; st > 0; st >>= 1) {
      bool up = ((lane & size) == 0);
      CEX(a0, st, up); CEX(a1, st, up);
      CEX(b0, st, up); CEX(b1, st, up);
    }
  }
  // ---- size 64 ----
  #pragma unroll
  for (int st = 32; st > 0; st >>= 1) {
    CEX(a0, st, true);  CEX(b0, st, true);
    CEX(a1, st, false); CEX(b1, st, false);
  }
  // ---- size 128 ----
  {
    bool up = ((wid & 1) == 0);
    CEXP(a0, a1, up); CEXP(b0, b1, up);
    #pragma unroll
    for (int st = 32; st > 0; st >>= 1) {
      CEX(a0, st, up); CEX(a1, st, up);
      CEX(b0, st, up); CEX(b1, st, up);
    }
  }
  // ---- sizes 256..2048 ----
  for (int size = 256; size <= 2048; size <<= 1) {
    arrA[e0] = a0; arrA[e1] = a1;
    arrB[e0] = b0; arrB[e1] = b1;
    __syncthreads();
    for (int st = size >> 1; st >= 128; st >>= 1) {
      int i = 2 * tid - (tid & (st - 1));
      int j = i + st;
      bool up2 = ((i & size) == 0);
      unsigned long long x0 = arrA[i], x1 = arrA[j];
      unsigned long long z0 = arrB[i], z1 = arrB[j];
      bool swA = up2 ? (x0 > x1) : (x0 < x1);
      bool swB = up2 ? (z0 > z1) : (z0 < z1);
      if (swA) { arrA[i] = x1; arrA[j] = x0; }
      if (swB) { arrB[i] = z1; arrB[j] = z0; }
      __syncthreads();
    }
    a0 = arrA[e0]; a1 = arrA[e1];
    b0 = arrB[e0]; b1 = arrB[e1];
    bool up = (((unsigned)(128 * wid) & (unsigned)size) == 0);
    CEXP(a0, a1, up); CEXP(b0, b1, up);
    #pragma unroll
    for (int st = 32; st > 0; st >>= 1) {
      CEX(a0, st, up); CEX(a1, st, up);
      CEX(b0, st, up); CEX(b1, st, up);
    }
  }

  // store sorted A for random access; B stays in registers
  arrA[e0] = a0; arrA[e1] = a1;
  __syncthreads();

  // compose permutations: fin = sortA_idx[ sortB_idx[i] ]
  {
    int s2i0 = (int)(b0 & 2047u);
    int fin0 = (int)(arrA[s2i0] & 2047u);
    yp[e0] = y[fin0] - offs[e0];
    if (e1 < N_SAMP) {
      int s2i1 = (int)(b1 & 2047u);
      int fin1 = (int)(arrA[s2i1] & 2047u);
      yp[e1] = y[fin1] - offs[e1];
    }
  }
  __syncthreads();

  // w = Xt * yp  (10 components, single-barrier reduce)
  double wloc[10];
  #pragma unroll
  for (int k = 0; k < 10; ++k) wloc[k] = 0.0;
  for (int i = tid; i < N_SAMP; i += NT) {
    double v = (double)yp[i];
    #pragma unroll
    for (int k = 0; k < 10; ++k) wloc[k] += (double)Xt[k * N_SAMP + i] * v;
  }
  #pragma unroll
  for (int k = 0; k < 10; ++k) {
    double v = wloc[k];
    #pragma unroll
    for (int off = 32; off > 0; off >>= 1) v += __shfl_xor(v, off, 64);
    if (lane == 0) redL[wid][k] = v;
  }
  __syncthreads();
  if (tid < 10) {
    double t = 0.0;
    for (int w2 = 0; w2 < 16; ++w2) t += redL[w2][tid];
    wf[tid] = t;
  }
  __syncthreads();
  if (tid < 10) {
    double m = 0.0;
    #pragma unroll
    for (int k = 0; k < 10; ++k) m += Mi[tid * 10 + k] * wf[k];
    mvd[tid] = m;
  }
  __syncthreads();

  // residualize + yty
  double acc = 0.0;
  for (int i = tid; i < N_SAMP; i += NT) {
    double d = (double)yp[i];
    #pragma unroll
    for (int k = 0; k < 10; ++k) d -= (double)Xt[k * N_SAMP + i] * mvd[k];
    float v = (float)d;
    if (Yt) Yt[(size_t)r * N_SAMP + i] = v;
    yp[i] = v;
    acc += (double)v * (double)v;
  }
  #pragma unroll
  for (int off = 32; off > 0; off >>= 1) acc += __shfl_xor(acc, off, 64);
  if (lane == 0) red16[wid] = acc;
  __syncthreads();
  if (tid == 0) {
    double tot = 0.0;
    for (int w2 = 0; w2 < 16; ++w2) tot += red16[w2];
    yty[r] = (float)tot;
    s[r] = 0u;
  }

  __syncthreads();
  if (yhi) {
    for (int i = tid; i < KPAD; i += NT) {
      float v = (i < N_SAMP) ? yp[i] : 0.f;
      unsigned short h, l;
      bf16split(v, h, l);
      yhi[(size_t)r * KPAD + i] = h;
      ylo[(size_t)r * KPAD + i] = l;
    }
  }
}

// ================= K5 (fallback): fp32 VALU GEMM ==============================
__global__ __launch_bounds__(256) void k5_gemm(
    const float* __restrict__ G, const float* __restrict__ Yt,
    const float* __restrict__ gg, unsigned* __restrict__ s) {
  __shared__ float As[16][64];
  __shared__ float Bs[16][68];
  int tid = threadIdx.x;
  int tx = tid & 15, ty = tid >> 4;
  int l0 = blockIdx.x * 64, r0 = blockIdx.y * 64;
  int a_row = tid >> 4;
  int a_col = (tid & 15) * 4;
  int b_row = tid >> 2;
  int b_col = (tid & 3) * 4;
  int gl = l0 + a_col;
  bool aval = (gl < L_VAR);
  int gr = r0 + b_row;
  bool bval = (gr < R_PERM);
  const float* gbase = G + (size_t)a_row * L_VAR + gl;
  const float* ybase = Yt + (size_t)gr * N_SAMP + b_col;

  float4 aR = aval ? *(const float4*)gbase : make_float4(0.f, 0.f, 0.f, 0.f);
  float4 bR = bval ? *(const float4*)ybase : make_float4(0.f, 0.f, 0.f, 0.f);

  float acc[4][4];
  #pragma unroll
  for (int u = 0; u < 4; ++u)
    #pragma unroll
    for (int v = 0; v < 4; ++v) acc[u][v] = 0.f;

  for (int i0 = 0; i0 < N_SAMP; i0 += 16) {
    *(float4*)&As[a_row][a_col] = aR;
    Bs[b_col + 0][b_row] = bR.x;
    Bs[b_col + 1][b_row] = bR.y;
    Bs[b_col + 2][b_row] = bR.z;
    Bs[b_col + 3][b_row] = bR.w;
    __syncthreads();
    int inext = i0 + 16;
    if (inext < N_SAMP) {
      aR = aval ? *(const float4*)(gbase + (size_t)inext * L_VAR) : make_float4(0.f, 0.f, 0.f, 0.f);
      bR = bval ? *(const float4*)(ybase + inext) : make_float4(0.f, 0.f, 0.f, 0.f);
    }
    #pragma unroll
    for (int k = 0; k < 16; ++k) {
      float4 av = *(const float4*)&As[k][tx * 4];
      float4 bv = *(const float4*)&Bs[k][ty * 4];
      float a4[4] = {av.x, av.y, av.z, av.w};
      float b4[4] = {bv.x, bv.y, bv.z, bv.w};
      #pragma unroll
      for (int u = 0; u < 4; ++u)
        #pragma unroll
        for (int v = 0; v < 4; ++v)
          acc[u][v] = fmaf(a4[u], b4[v], acc[u][v]);
    }
    __syncthreads();
  }
  #pragma unroll
  for (int v = 0; v < 4; ++v) {
    int rr = r0 + ty * 4 + v;
    float m = 0.f;
    #pragma unroll
    for (int u = 0; u < 4; ++u) {
      int ll = l0 + tx * 4 + u;
      if (ll < L_VAR) {
        float U = acc[u][v];
        float t = U * U / gg[ll];
        m = fmaxf(m, t);
      }
    }
    #pragma unroll
    for (int off = 8; off > 0; off >>= 1) m = fmaxf(m, __shfl_xor(m, off, 64));
    if (tx == 0 && rr < R_PERM) atomicMax(&s[rr], __float_as_uint(m));
  }
}

// ===== K5F (big): 3-deep pipelined bf16x3 MFMA GEMM (round-8 best config) =====
// Tile 64l x 128r, grid 314, LDS ~72 KB, triple-buffered, raw s_barrier +
// counted s_waitcnt vmcnt(12). Round-11b: k3t folded in -- rgg for this
// block's 64 l's computed post-loop from XtGp2/GGp2/Mi (bit-identical math).
__device__ __forceinline__ void k5f_stage(
    int w, int lane, int kb, int l0, int rbase,
    const unsigned short* __restrict__ GTHI, const unsigned short* __restrict__ GTLO,
    const unsigned short* __restrict__ YHI, const unsigned short* __restrict__ YLO,
    unsigned short* Ah, unsigned short* Al, unsigned short* Bh, unsigned short* Bl) {
  int sub = lane >> 2, kq = lane & 3;
  #pragma unroll
  for (int j = 0; j < 6; ++j) {
    int c = w * 6 + j;
    const unsigned short* src;
    unsigned short* dst;
    if (c < 4) {
      src = GTHI + (size_t)(l0 + c * 16 + sub) * KPAD + kb + kq * 8;
      dst = Ah + c * 512 + lane * 8;
    } else if (c < 8) {
      src = GTLO + (size_t)(l0 + (c - 4) * 16 + sub) * KPAD + kb + kq * 8;
      dst = Al + (c - 4) * 512 + lane * 8;
    } else if (c < 16) {
      src = YHI + (size_t)(rbase + (c - 8) * 16 + sub) * KPAD + kb + kq * 8;
      dst = Bh + (c - 8) * 512 + lane * 8;
    } else {
      src = YLO + (size_t)(rbase + (c - 16) * 16 + sub) * KPAD + kb + kq * 8;
      dst = Bl + (c - 16) * 512 + lane * 8;
    }
    __builtin_amdgcn_global_load_lds(
        (const __attribute__((address_space(1))) unsigned int*)(const void*)src,
        (__attribute__((address_space(3))) unsigned int*)(void*)dst, 16, 0, 0);
  }
}

__global__ __launch_bounds__(256) void k5f_mfma(
    const unsigned short* __restrict__ GTHI, const unsigned short* __restrict__ GTLO,
    const unsigned short* __restrict__ YHI, const unsigned short* __restrict__ YLO,
    const float* __restrict__ XtGp2, const float* __restrict__ GGp2,
    const double* __restrict__ Mi, unsigned* __restrict__ s) {
  __shared__ unsigned short Ah[3][64 * 32];
  __shared__ unsigned short Al[3][64 * 32];
  __shared__ unsigned short Bh[3][128 * 32];
  __shared__ unsigned short Bl[3][128 * 32];
  __shared__ float rl_sh[64];
  int tid = threadIdx.x;
  int w = tid >> 6, lane = tid & 63;
  int row16 = lane & 15, quad = lane >> 4;
  int ltile = blockIdx.x >> 1;
  int rhalf = blockIdx.x & 1;
  int l0 = ltile * 64;
  int rbase = rhalf * 128;

  float4v acc[4][2];
  #pragma unroll
  for (int mt = 0; mt < 4; ++mt)
    #pragma unroll
    for (int nt = 0; nt < 2; ++nt)
      acc[mt][nt] = (float4v){0.f, 0.f, 0.f, 0.f};

  // prologue: fill the 3-deep pipeline (18 outstanding loads per wave)
  k5f_stage(w, lane, 0,  l0, rbase, GTHI, GTLO, YHI, YLO, Ah[0], Al[0], Bh[0], Bl[0]);
  k5f_stage(w, lane, 32, l0, rbase, GTHI, GTLO, YHI, YLO, Ah[1], Al[1], Bh[1], Bl[1]);
  k5f_stage(w, lane, 64, l0, rbase, GTHI, GTLO, YHI, YLO, Ah[2], Al[2], Bh[2], Bl[2]);

  #pragma unroll 1
  for (int step = 0; step < 64; ++step) {
    int cur = step % 3;
    // wait for THIS step's 6 per-wave loads (oldest); keep up to 12 in flight.
    if (step < 62) {
      asm volatile("s_waitcnt vmcnt(12)" ::: "memory");
    } else if (step == 62) {
      asm volatile("s_waitcnt vmcnt(6)" ::: "memory");
    } else {
      asm volatile("s_waitcnt vmcnt(0)" ::: "memory");
    }
    __builtin_amdgcn_s_barrier();   // all waves' step data now visible
    __builtin_amdgcn_sched_barrier(0);

    short8v ahf[4], alf[4], bhf[2], blf[2];
    #pragma unroll
    for (int mt = 0; mt < 4; ++mt) {
      int o = (mt * 16 + row16) * 32 + quad * 8;
      ahf[mt] = *(const short8v*)&Ah[cur][o];
      alf[mt] = *(const short8v*)&Al[cur][o];
    }
    #pragma unroll
    for (int nt = 0; nt < 2; ++nt) {
      int o = (w * 32 + nt * 16 + row16) * 32 + quad * 8;
      bhf[nt] = *(const short8v*)&Bh[cur][o];
      blf[nt] = *(const short8v*)&Bl[cur][o];
    }
    #pragma unroll
    for (int nt = 0; nt < 2; ++nt) {
      #pragma unroll
      for (int mt = 0; mt < 4; ++mt) {
        acc[mt][nt] = __builtin_amdgcn_mfma_f32_16x16x32_bf16(ahf[mt], bhf[nt], acc[mt][nt], 0, 0, 0);
        acc[mt][nt] = __builtin_amdgcn_mfma_f32_16x16x32_bf16(ahf[mt], blf[nt], acc[mt][nt], 0, 0, 0);
        acc[mt][nt] = __builtin_amdgcn_mfma_f32_16x16x32_bf16(alf[mt], bhf[nt], acc[mt][nt], 0, 0, 0);
      }
    }
    // all waves done READING buf[cur]; refill it with step+3.
    __builtin_amdgcn_s_barrier();
    if (step + 3 < 64)
      k5f_stage(w, lane, (step + 3) * 32, l0, rbase, GTHI, GTLO, YHI, YLO,
                Ah[cur], Al[cur], Bh[cur], Bl[cur]);
  }

  // folded k3t: rgg for this block's 64 l's (matches k3t_gg math exactly)
  if (tid < 64) {
    int l = l0 + tid;
    double t[10]; double g2d = 0.0;
    #pragma unroll
    for (int k = 0; k < 10; ++k) t[k] = 0.0;
    for (int part = 0; part < 16; ++part) {
      #pragma unroll
      for (int k = 0; k < 10; ++k)
        t[k] += (double)XtGp2[((size_t)part * 10 + k) * LPAD + l];
      g2d += (double)GGp2[(size_t)part * LPAD + l];
    }
    double corr = 0.0;
    #pragma unroll
    for (int k = 0; k < 10; ++k) {
      double a = 0.0;
      #pragma unroll
      for (int j = 0; j < 10; ++j) a += Mi[k * 10 + j] * t[j];
      corr += a * t[k];
    }
    double v = g2d - corr;
    rl_sh[tid] = (v > 0.0) ? (float)(1.0 / v) : 0.f;
  }
  __syncthreads();

  // epilogue: wave owns 64l x 32r at (l0, rbase + w*32)
  float rl_[4][4];
  #pragma unroll
  for (int mt = 0; mt < 4; ++mt)
    #pragma unroll
    for (int q = 0; q < 4; ++q)
      rl_[mt][q] = rl_sh[mt * 16 + quad * 4 + q];
  #pragma unroll
  for (int nt = 0; nt < 2; ++nt) {
    float m = 0.f;
    #pragma unroll
    for (int mt = 0; mt < 4; ++mt)
      #pragma unroll
      for (int q = 0; q < 4; ++q) {
        float U = acc[mt][nt][q];
        m = fmaxf(m, U * U * rl_[mt][q]);
      }
    m = fmaxf(m, __shfl_xor(m, 16, 64));
    m = fmaxf(m, __shfl_xor(m, 32, 64));
    int r = rbase + w * 32 + nt * 16 + row16;
    if (quad == 0 && r < R_PERM) atomicMax(&s[r], __float_as_uint(m));
  }
}

// ================= K6: TS^2 -> p -> MoM + lane-parallel Newton -> betainc =====
__global__ __launch_bounds__(256) void k6_final(
    const unsigned* __restrict__ sbits, const float* __restrict__ yty,
    const float* __restrict__ minp, float* __restrict__ out) {
  __shared__ double red[256];
  int tid = threadIdx.x;
  double p = 0.0, p2 = 0.0, lp = 0.0, l1p = 0.0;
  if (tid < R_PERM) {
    double t = (double)__uint_as_float(sbits[tid]);
    double Y = (double)yty[tid];
    double ts2 = DOF_D * t / (Y - t);
    double pp = erfc(sqrt(0.5 * ts2));
    p = pp; p2 = pp * pp; lp = log(pp); l1p = log1p(-pp);
  }
  double Sp  = breduce_add(p, red, tid);
  double Sp2 = breduce_add(p2, red, tid);
  double S1  = breduce_add(lp, red, tid);
  double S2  = breduce_add(l1p, red, tid);
  if (tid < 64) {
    const double nobs = (double)R_PERM;
    double mean = Sp / nobs;
    double var = Sp2 / nobs - mean * mean;
    double k = mean * (mean * (1.0 - mean) / var - 1.0);
    double n = k * (1.0 / mean - 1.0);
    double old_lik = 10000.0, diff = 1000.0;
    int iter = 0;
    int sel = tid % 3, grp = tid / 3;
    while (fabs(diff) > 1e-3 && iter <= 100) {
      double arg = (sel == 0) ? k : (sel == 1) ? n : (k + n);
      double v = 0.0;
      if (grp == 0) v = dg_trigamma(arg);
      else if (grp == 1) v = dg_tetragamma(arg);
      else if (grp == 2) v = dg_digamma(arg);
      double pg1k = __shfl(v, 0, 64), pg1n = __shfl(v, 1, 64), pg1kn = __shfl(v, 2, 64);
      double pg2k = __shfl(v, 3, 64), pg2n = __shfl(v, 4, 64), pg2kn = __shfl(v, 5, 64);
      double dgk  = __shfl(v, 6, 64), dgn  = __shfl(v, 7, 64), dgkn  = __shfl(v, 8, 64);
      double i_kn = -pg1kn, i_k = pg1k + i_kn, i_n = pg1n + i_kn;
      double A = -nobs * i_k, B = -nobs * i_kn, C = -nobs * i_n;
      double s0 = S1 - nobs * (dgk - dgkn);
      double s1 = S2 - nobs * (dgn - dgkn);
      double det = A * C - B * B;
      double d0 = (C * s0 - B * s1) / det;
      double d1 = (A * s1 - B * s0) / det;
      double i_kkn = pg1n * pg2kn;
      double g_k = -pg1n * pg2k + i_kkn + pg1kn * pg2k;
      double i_knn = i_kkn - pg1kn * pg2n;
      double i_nnk = pg1k * pg2kn;
      double i_nkk = i_nnk - pg1kn * pg2k;
      double g_n = -pg1k * pg2n + i_nnk + pg1kn * pg2n;
      double scale = -pg1k * pg1n + (pg1k + pg1n) * pg1kn;
      double f = 0.5 / scale;
      double adj0 = f * (g_k * d0 * d0 + 2.0 * i_kkn * d0 * d1 + i_knn * d1 * d1);
      double adj1 = f * (i_nkk * d0 * d0 + 2.0 * i_nnk * d0 * d1 + g_n * d1 * d1);
      double nk_ = k - d0 - 0.5 * adj0;
      double nn_ = n - d1 - 0.5 * adj1;
      double arg2 = (tid == 0) ? nk_ : (tid == 1) ? nn_ : (nk_ + nn_);
      double lg = (tid < 3) ? lgamma(arg2) : 0.0;
      double lgk = __shfl(lg, 0, 64), lgn = __shfl(lg, 1, 64), lgkn = __shfl(lg, 2, 64);
      double nl = (nk_ - 1.0) * S1 + (nn_ - 1.0) * S2 - nobs * (lgk + lgn - lgkn);
      diff = old_lik - nl;
      old_lik = nl; k = nk_; n = nn_; ++iter;
    }
    if (tid == 0) {
      double conv = (fabs(diff) < 1e-3 && iter <= 100) ? 1.0 : 0.0;
      double adj = betainc_d(k, n, (double)(*minp));
      out[0] = (float)adj;
      out[1] = (float)k;
      out[2] = (float)n;
      out[3] = (float)conv;
    }
  }
}

__global__ void k_err(float* out) {
  if (threadIdx.x < 4) out[threadIdx.x] = -12345.0f;
}

extern "C" void kernel_launch(void* const* d_in, const int* in_sizes, int n_in,
                              void* d_out, int out_size, void* d_ws, size_t ws_size,
                              hipStream_t stream) {
  const float* X     = (const float*)d_in[0];
  const float* y     = (const float*)d_in[1];
  const float* G     = (const float*)d_in[2];
  const float* obs_p = (const float*)d_in[3];
  const float* offs  = (const float*)d_in[4];
  const int*   seedp = (const int*)d_in[5];
  float* out = (float*)d_out;

  if (ws_size < WS_OLD) {
    k_err<<<1, 64, 0, stream>>>(out);
    return;
  }
  char* ws = (char*)d_ws;
  unsigned* pkeys = (unsigned*)(ws + OFF_PKEYS);
  double*   Mi    = (double*)(ws + OFF_MI);
  float*    minp  = (float*)(ws + OFF_MINP);
  float*    Xt    = (float*)(ws + OFF_XT);
  float*    XtGp  = (float*)(ws + OFF_XTGP);
  float*    GGp   = (float*)(ws + OFF_GGP);
  float*    gg    = (float*)(ws + OFF_GG);
  float*    yty   = (float*)(ws + OFF_YTY);
  unsigned* s     = (unsigned*)(ws + OFF_S);
  float*    Yt    = (float*)(ws + OFF_YT);

  bool big = (ws_size >= WS_BIG);
  unsigned short* yhi   = big ? (unsigned short*)(ws + OFF_YHI) : nullptr;
  unsigned short* ylo   = big ? (unsigned short*)(ws + OFF_YLO) : nullptr;
  float*          XtGp2 = big ? (float*)(ws + OFF_XTGP2) : nullptr;
  float*          GGp2  = big ? (float*)(ws + OFF_GGP2) : nullptr;
  unsigned short* GTHI  = big ? (unsigned short*)(ws + OFF_GTHI) : nullptr;
  unsigned short* GTLO  = big ? (unsigned short*)(ws + OFF_GTLO) : nullptr;

  if (big) {
    // k1's 59 role-blocks fused into k2t (x in [158,217), y==0) -> one launch
    k2t_pass<<<dim3(158 + 59, 16), 256, 0, stream>>>(
        G, X, obs_p, seedp, GTHI, GTLO, XtGp2, GGp2, pkeys,
        Xt, Mi, minp, yhi, ylo);
    // big path: skip fallback-Yt write (region overlaps YHI) -> pass nullptr
    k4_perm<<<R_PERM, 1024, 0, stream>>>(y, offs, Xt, pkeys, Mi, nullptr, yty, s, yhi, ylo);
    // k3t folded into k5f (rgg computed per-block from XtGp2/GGp2/Mi)
    k5f_mfma<<<314, 256, 0, stream>>>(GTHI, GTLO, yhi, ylo, XtGp2, GGp2, Mi, s);
  } else {
    k1_setup<<<3, 256, 0, stream>>>(X, obs_p, Xt, Mi, minp, nullptr, nullptr);
    k2_xtg<<<dim3(41, 5), 256, 0, stream>>>(G, X, seedp, XtGp, GGp, pkeys);
    k3_gg<<<40, 256, 0, stream>>>(XtGp, GGp, Mi, gg);
    k4_perm<<<R_PERM, 1024, 0, stream>>>(y, offs, Xt, pkeys, Mi, Yt, yty, s, nullptr, nullptr);
    k5_gemm<<<dim3(157, 4), 256, 0, stream>>>(G, Yt, gg, s);
  }
  k6_final<<<1, 256, 0, stream>>>(s, yty, minp, out);
}

// Round 13
// 284.834 us; speedup vs baseline: 1.2958x; 1.0319x over previous
//
#include <hip/hip_runtime.h>
#include <stdint.h>

// PRNG variant: 1 = jax_threefry_partitionable=True (JAX >= 0.4.36 default)
#ifndef JAX_THREEFRY_PARTITIONABLE
#define JAX_THREEFRY_PARTITIONABLE 1
#endif

#define N_SAMP 2000
#define L_VAR  10000
#define R_PERM 200
#define DOF_D  1989.0   // N - K - 1

#define KPAD   2048     // padded K (samples) for MFMA path
#define LPAD   10048    // padded L (157*64)
#define RPAD   256      // padded R

// ---------------- workspace layout (bytes) ----------------
#define OFF_PKEYS  0UL
#define OFF_MI     1664UL
#define OFF_MINP   2464UL
#define OFF_XT     2560UL
#define OFF_XTGP   82560UL     // fallback only
#define OFF_GGP    2082560UL   // fallback only
#define OFF_GG     2282560UL
#define OFF_YTY    2322560UL
#define OFF_S      2323392UL
#define OFF_YT     2324224UL   // fallback only (big path overlaps with YHI)
#define WS_OLD     3924224UL
#define OFF_GGP2   82560UL     // float[16][10048] = 643,072 (over fallback XTGP)
#define OFF_RGG    725632UL    // float[10048]
#define OFF_YHI    2324224UL   // u16[256][2048] = 1,048,576 (over fallback YT)
#define OFF_XTGP2  3924224UL   // float[16][10][10048] = 6,430,720
#define OFF_YLO    10354944UL  // u16[256][2048]
#define OFF_GTHI   11403520UL  // u16[10048][2048] = 41,156,608
#define OFF_GTLO   52560128UL  // u16[10048][2048] -> ends 93,716,736
#define WS_BIG     95186432UL  // known good

typedef __attribute__((ext_vector_type(8))) short short8v;   // 8 bf16
typedef __attribute__((ext_vector_type(4))) float float4v;   // MFMA acc

// ---------------- threefry2x32, JAX-exact ----------------
__device__ __forceinline__ uint32_t rotl32(uint32_t v, int d) {
  return (v << d) | (v >> (32 - d));
}
__device__ __forceinline__ uint2 tf2(uint32_t k0, uint32_t k1, uint32_t x0, uint32_t x1) {
  uint32_t ks2 = k0 ^ k1 ^ 0x1BD11BDAu;
  x0 += k0; x1 += k1;
#define TF4(a,b,c,d) \
  x0 += x1; x1 = rotl32(x1,a); x1 ^= x0; \
  x0 += x1; x1 = rotl32(x1,b); x1 ^= x0; \
  x0 += x1; x1 = rotl32(x1,c); x1 ^= x0; \
  x0 += x1; x1 = rotl32(x1,d); x1 ^= x0;
  TF4(13,15,26,6)  x0 += k1;  x1 += ks2 + 1u;
  TF4(17,29,16,24) x0 += ks2; x1 += k0 + 2u;
  TF4(13,15,26,6)  x0 += k0;  x1 += k1 + 3u;
  TF4(17,29,16,24) x0 += k1;  x1 += ks2 + 4u;
  TF4(13,15,26,6)  x0 += ks2; x1 += k0 + 5u;
#undef TF4
  return make_uint2(x0, x1);
}

// single-thread fallback key chain
__device__ __forceinline__ void gen_pkeys(const int* seedp, unsigned* pkeys) {
  uint32_t khi = 0u, klo = (uint32_t)(*seedp);
  for (int r = 0; r < R_PERM; ++r) {
#if JAX_THREEFRY_PARTITIONABLE
    uint2 pk = tf2(khi, klo, 0u, 1u);
    uint2 nk = tf2(khi, klo, 0u, 0u);
#else
    uint2 t0 = tf2(khi, klo, 0u, 2u);
    uint2 t1 = tf2(khi, klo, 1u, 3u);
    uint2 nk = make_uint2(t0.x, t1.x);
    uint2 pk = make_uint2(t0.y, t1.y);
#endif
    pkeys[2 * r] = pk.x; pkeys[2 * r + 1] = pk.y;
    khi = nk.x; klo = nk.y;
  }
}

// ---------------- block reduce (256 threads, for k6) ----------------
__device__ __forceinline__ double breduce_add(double v, double* red, int tid) {
  red[tid] = v; __syncthreads();
  for (int off = 128; off > 0; off >>= 1) {
    if (tid < off) red[tid] += red[tid + off];
    __syncthreads();
  }
  double r = red[0]; __syncthreads();
  return r;
}

// ---------------- special functions (double) ----------------
__device__ double dg_digamma(double x) {
  if (!(x > 0.0)) return __builtin_nan("");
  double r = 0.0;
  while (x < 8.0) { r -= 1.0 / x; x += 1.0; }
  double t = 1.0 / x, t2 = t * t;
  double ser = t2 * (1.0/12.0 - t2*(1.0/120.0 - t2*(1.0/252.0 - t2*(1.0/240.0 - t2*(1.0/132.0)))));
  return r + log(x) - 0.5 * t - ser;
}
__device__ double dg_trigamma(double x) {
  if (!(x > 0.0)) return __builtin_nan("");
  double r = 0.0;
  while (x < 8.0) { r += 1.0 / (x * x); x += 1.0; }
  double t = 1.0 / x, t2 = t * t;
  double P = 1.0/6.0 - t2*(1.0/30.0 - t2*(1.0/42.0 - t2*(1.0/30.0 - t2*(5.0/66.0))));
  return r + t + 0.5 * t2 + t * t2 * P;
}
__device__ double dg_tetragamma(double x) {
  if (!(x > 0.0)) return __builtin_nan("");
  double r = 0.0;
  while (x < 8.0) { r -= 2.0 / (x * x * x); x += 1.0; }
  double t = 1.0 / x, t2 = t * t;
  double Q = 1.0 + t + 0.5*t2 - t2*t2*(1.0/6.0 - t2*(1.0/6.0 - t2*(3.0/10.0)));
  return r - t2 * Q;
}
__device__ double betacf_d(double a, double b, double x) {
  const double FPMIN = 1e-300, EPS = 3e-16;
  double qab = a + b, qap = a + 1.0, qam = a - 1.0;
  double c = 1.0, d = 1.0 - qab * x / qap;
  if (fabs(d) < FPMIN) d = FPMIN;
  d = 1.0 / d; double h = d;
  for (int m = 1; m <= 300; ++m) {
    int m2 = 2 * m;
    double aa = m * (b - m) * x / ((qam + m2) * (a + m2));
    d = 1.0 + aa * d; if (fabs(d) < FPMIN) d = FPMIN;
    c = 1.0 + aa / c; if (fabs(c) < FPMIN) c = FPMIN;
    d = 1.0 / d; double del = d * c; h *= del;
    aa = -(a + m) * (qab + m) * x / ((a + m2) * (qap + m2));
    d = 1.0 + aa * d; if (fabs(d) < FPMIN) d = FPMIN;
    c = 1.0 + aa / c; if (fabs(c) < FPMIN) c = FPMIN;
    d = 1.0 / d; del = d * c; h *= del;
    if (fabs(del - 1.0) < EPS) break;
  }
  return h;
}
__device__ double betainc_d(double a, double b, double x) {
  if (!(x > 0.0)) return 0.0;
  if (x >= 1.0) return 1.0;
  double lnbt = lgamma(a + b) - lgamma(a) - lgamma(b) + a * log(x) + b * log1p(-x);
  double bt = exp(lnbt);
  if (x < (a + 1.0) / (a + b + 2.0)) return bt * betacf_d(a, b, x) / a;
  else return 1.0 - bt * betacf_d(b, a, 1.0 - x) / b;
}

__device__ __forceinline__ void tri_ab(int q, int& a, int& b) {
  int aa = 0, rem = q;
  while (rem >= 10 - aa) { rem -= 10 - aa; ++aa; }
  a = aa; b = aa + rem;
}

// split fp32 -> bf16 hi + bf16 lo (truncation split)
__device__ __forceinline__ void bf16split(float f, unsigned short& h, unsigned short& l) {
  unsigned u = __float_as_uint(f);
  h = (unsigned short)(u >> 16);
  float rem = f - __uint_as_float(u & 0xFFFF0000u);
  l = (unsigned short)(__float_as_uint(rem) >> 16);
}

// per-element sort key (matches original fill_keys exactly)
__device__ __forceinline__ unsigned long long keyfor(uint32_t kx, uint32_t ky, int e) {
  if (e >= N_SAMP) return ~0ull;
#if JAX_THREEFRY_PARTITIONABLE
  uint2 o = tf2(kx, ky, 0u, (uint32_t)e);
  uint32_t bits = o.x ^ o.y;
  return (((unsigned long long)bits) << 11) | (unsigned long long)e;
#else
  uint2 o = (e < 1000) ? tf2(kx, ky, (uint32_t)e, (uint32_t)(1000 + e))
                       : tf2(kx, ky, (uint32_t)(e - 1000), (uint32_t)e);
  uint32_t bits = (e < 1000) ? o.x : o.y;
  return (((unsigned long long)bits) << 11) | (unsigned long long)e;
#endif
}

// ---- shared k1 role body (used by standalone k1 and fused into k2t) ---------
__device__ void k1_role(
    int role, int tid,
    const float* __restrict__ X, const float* __restrict__ obs_p,
    float* __restrict__ Xt, double* __restrict__ Mi, float* __restrict__ minp,
    unsigned short* __restrict__ yhi, unsigned short* __restrict__ ylo) {
  if (role == 0) {
    __shared__ double wsum[4][55];
    __shared__ double xtx_sh[55];
    __shared__ double A[10][21];
    __shared__ int piv_sh;
    __shared__ double pv_sh;
    int wave = tid >> 6, lane = tid & 63;

    double acc[55];
    #pragma unroll
    for (int q = 0; q < 55; ++q) acc[q] = 0.0;
    for (int i = tid; i < N_SAMP; i += 256) {
      float xv[10];
      #pragma unroll
      for (int k = 0; k < 5; ++k) {
        float2 t2 = *(const float2*)(X + i * 10 + 2 * k);
        xv[2 * k] = t2.x; xv[2 * k + 1] = t2.y;
      }
      int q = 0;
      #pragma unroll
      for (int a = 0; a < 10; ++a)
        #pragma unroll
        for (int b = a; b < 10; ++b)
          acc[q++] += (double)xv[a] * (double)xv[b];
    }
    #pragma unroll
    for (int q = 0; q < 55; ++q) {
      double v = acc[q];
      #pragma unroll
      for (int off = 32; off > 0; off >>= 1) v += __shfl_xor(v, off, 64);
      if (lane == 0) wsum[wave][q] = v;
    }
    __syncthreads();
    if (tid < 55) xtx_sh[tid] = wsum[0][tid] + wsum[1][tid] + wsum[2][tid] + wsum[3][tid];
    __syncthreads();

    if (tid < 200) {
      int r = tid / 20, j = tid % 20;
      double v;
      if (j < 10) {
        int a = r < j ? r : j;
        int b = r < j ? j : r;
        int q = 10 * a - a * (a - 1) / 2 + (b - a);
        v = xtx_sh[q];
      } else {
        v = (j - 10 == r) ? 1.0 : 0.0;
      }
      A[r][j] = v;
    }
    __syncthreads();
    int r_ = tid / 20, j_ = tid % 20;
    bool in200 = (tid < 200);
    for (int c = 0; c < 10; ++c) {
      if (tid == 0) {
        int piv = c; double best = fabs(A[c][c]);
        for (int r2 = c + 1; r2 < 10; ++r2)
          if (fabs(A[r2][c]) > best) { best = fabs(A[r2][c]); piv = r2; }
        piv_sh = piv;
      }
      __syncthreads();
      int piv = piv_sh;
      if (piv != c && tid < 20) {
        double t = A[c][tid]; A[c][tid] = A[piv][tid]; A[piv][tid] = t;
      }
      __syncthreads();
      if (tid == 0) pv_sh = A[c][c];
      __syncthreads();
      if (tid < 20) A[c][tid] *= (1.0 / pv_sh);
      __syncthreads();
      double f = 0.0, acj = 0.0;
      bool act = in200 && (r_ != c);
      if (act) { f = A[r_][c]; acj = A[c][j_]; }
      __syncthreads();
      if (act) A[r_][j_] -= f * acj;
      __syncthreads();
    }
    if (tid < 100) Mi[tid] = A[tid / 10][10 + (tid % 10)];
  } else if (role == 1) {
    __shared__ float redf[256];
    float m = 1e30f;
    for (int i = tid; i < L_VAR; i += 256) m = fminf(m, obs_p[i]);
    redf[tid] = m; __syncthreads();
    for (int off = 128; off > 0; off >>= 1) {
      if (tid < off) redf[tid] = fminf(redf[tid], redf[tid + off]);
      __syncthreads();
    }
    if (tid == 0) *minp = redf[0];
  } else if (role == 2) {
    for (int idx = tid; idx < 10 * N_SAMP; idx += 256) {
      int k = idx / N_SAMP, i = idx - k * N_SAMP;
      Xt[idx] = X[i * 10 + k];
    }
  } else {
    // roles 3..58: zero bf16 Yt pad rows 200..255 (big path only)
    if (yhi) {
      int row = R_PERM + (role - 3);
      size_t base = (size_t)row * KPAD;
      for (int i = tid; i < KPAD; i += 256) {
        yhi[base + i] = 0;
        ylo[base + i] = 0;
      }
    }
  }
}

// ====== K1 (fallback path standalone) ========================================
__global__ __launch_bounds__(256) void k1_setup(
    const float* __restrict__ X, const float* __restrict__ obs_p,
    float* __restrict__ Xt, double* __restrict__ Mi, float* __restrict__ minp,
    unsigned short* __restrict__ yhi, unsigned short* __restrict__ ylo) {
  k1_role((int)blockIdx.x, (int)threadIdx.x, X, obs_p, Xt, Mi, minp, yhi, ylo);
}

// ================= K2 (fallback): XtG/GG partials + key chain =================
__global__ __launch_bounds__(256) void k2_xtg(
    const float* __restrict__ G, const float* __restrict__ X,
    const int* __restrict__ seedp, float* __restrict__ XtGp,
    float* __restrict__ GGp, unsigned* __restrict__ pkeys) {
  if (blockIdx.x == 40) {
    if (blockIdx.y == 0 && threadIdx.x == 0) gen_pkeys(seedp, pkeys);
    return;
  }
  int l = blockIdx.x * 256 + threadIdx.x;
  bool valid = (l < L_VAR);
  int i0 = blockIdx.y * 400;
  float acc[10];
  #pragma unroll
  for (int k = 0; k < 10; ++k) acc[k] = 0.f;
  float g2 = 0.f;
  for (int i = i0; i < i0 + 400; ++i) {
    float g = valid ? G[(size_t)i * L_VAR + l] : 0.f;
    #pragma unroll
    for (int k = 0; k < 10; ++k) acc[k] = fmaf(g, X[i * 10 + k], acc[k]);
    g2 = fmaf(g, g, g2);
  }
  if (valid) {
    int part = blockIdx.y;
    #pragma unroll
    for (int k = 0; k < 10; ++k)
      XtGp[((size_t)part * 10 + k) * L_VAR + l] = acc[k];
    GGp[(size_t)part * L_VAR + l] = g2;
  }
}

// ===== K2T (big): G pass -> G^T bf16 hi/lo + XtG/GG partials + key chain =====
// k1's 59 blocks fused in at blockIdx.x in [158,217), y==0 only.
__global__ __launch_bounds__(256) void k2t_pass(
    const float* __restrict__ G, const float* __restrict__ X,
    const float* __restrict__ obs_p, const int* __restrict__ seedp,
    unsigned short* __restrict__ GTHI, unsigned short* __restrict__ GTLO,
    float* __restrict__ XtGp2, float* __restrict__ GGp2,
    unsigned* __restrict__ pkeys,
    float* __restrict__ Xt, double* __restrict__ Mi, float* __restrict__ minp,
    unsigned short* __restrict__ yhi, unsigned short* __restrict__ ylo) {
  if (blockIdx.x >= 158) {
    if (blockIdx.y != 0) return;
    k1_role((int)blockIdx.x - 158, (int)threadIdx.x, X, obs_p, Xt, Mi, minp, yhi, ylo);
    return;
  }
  if (blockIdx.x == 157) {
    // 2-lane parallel key chain
    if (blockIdx.y == 0 && threadIdx.x < 2) {
      int t = threadIdx.x;
      uint32_t khi = 0u, klo = (uint32_t)(*seedp);
#if JAX_THREEFRY_PARTITIONABLE
      for (int r = 0; r < R_PERM; ++r) {
        uint2 res = tf2(khi, klo, 0u, (uint32_t)t);   // t=0 -> nk, t=1 -> pk
        if (t == 1) { pkeys[2 * r] = res.x; pkeys[2 * r + 1] = res.y; }
        khi = __shfl(res.x, 0, 64);
        klo = __shfl(res.y, 0, 64);
      }
#else
      if (t == 0) gen_pkeys(seedp, pkeys);
#endif
    }
    return;
  }
  __shared__ float T[128][69];
  __shared__ float Xsh[128][10];
  int tid = threadIdx.x;
  int l0 = blockIdx.x * 64, i0 = blockIdx.y * 128;
  for (int it = 0; it < 8; ++it) {
    int fi = it * 256 + tid;
    int row = fi >> 4, c4 = (fi & 15) * 4;
    int i = i0 + row, l = l0 + c4;
    float4 v = make_float4(0.f, 0.f, 0.f, 0.f);
    if (i < N_SAMP && l + 3 < L_VAR) v = *(const float4*)(G + (size_t)i * L_VAR + l);
    T[row][c4 + 0] = v.x; T[row][c4 + 1] = v.y; T[row][c4 + 2] = v.z; T[row][c4 + 3] = v.w;
  }
  for (int q = 0; q < 5; ++q) {
    int idx = q * 256 + tid;
    if (idx < 1280) {
      int row = idx / 10, k = idx - row * 10;
      int i = i0 + row;
      Xsh[row][k] = (i < N_SAMP) ? X[i * 10 + k] : 0.f;
    }
  }
  __syncthreads();
  {
    int w = tid >> 6, lam = tid & 63;
    int half = lam >> 5, i4 = (lam & 31) * 4;
    for (int g = 0; g < 8; ++g) {
      int lloc = g * 8 + w * 2 + half;
      float fv[4];
      fv[0] = T[i4 + 0][lloc]; fv[1] = T[i4 + 1][lloc];
      fv[2] = T[i4 + 2][lloc]; fv[3] = T[i4 + 3][lloc];
      ushort4 hv, lv;
      bf16split(fv[0], hv.x, lv.x);
      bf16split(fv[1], hv.y, lv.y);
      bf16split(fv[2], hv.z, lv.z);
      bf16split(fv[3], hv.w, lv.w);
      size_t idx = (size_t)(l0 + lloc) * KPAD + i0 + i4;
      *(ushort4*)(GTHI + idx) = hv;
      *(ushort4*)(GTLO + idx) = lv;
    }
  }
  int lc = tid & 63, iq = tid >> 6;
  float accx[10];
  #pragma unroll
  for (int k = 0; k < 10; ++k) accx[k] = 0.f;
  float g2 = 0.f;
  for (int j = 0; j < 32; ++j) {
    int i = iq * 32 + j;
    float tv = T[i][lc];
    g2 = fmaf(tv, tv, g2);
    #pragma unroll
    for (int k = 0; k < 10; ++k) accx[k] = fmaf(tv, Xsh[i][k], accx[k]);
  }
  __syncthreads();
  float* scr = &T[0][0];
  #pragma unroll
  for (int k = 0; k < 10; ++k) scr[(iq * 64 + lc) * 10 + k] = accx[k];
  scr[2560 + iq * 64 + lc] = g2;
  __syncthreads();
  for (int idx = tid; idx < 640; idx += 256) {
    int l = idx / 10, k = idx - l * 10;
    float t = scr[(0 * 64 + l) * 10 + k] + scr[(1 * 64 + l) * 10 + k]
            + scr[(2 * 64 + l) * 10 + k] + scr[(3 * 64 + l) * 10 + k];
    XtGp2[((size_t)blockIdx.y * 10 + k) * LPAD + l0 + l] = t;
  }
  if (tid < 64) {
    float s4 = scr[2560 + tid] + scr[2560 + 64 + tid] + scr[2560 + 128 + tid] + scr[2560 + 192 + tid];
    GGp2[(size_t)blockIdx.y * LPAD + l0 + tid] = s4;
  }
}

// ================= K3 (fallback) ==============================================
__global__ __launch_bounds__(256) void k3_gg(
    const float* __restrict__ XtGp, const float* __restrict__ GGp,
    const double* __restrict__ Mi, float* __restrict__ gg) {
  int l = blockIdx.x * 256 + threadIdx.x;
  if (l >= L_VAR) return;
  double t[10]; double g2 = 0.0;
  #pragma unroll
  for (int k = 0; k < 10; ++k) t[k] = 0.0;
  for (int part = 0; part < 5; ++part) {
    #pragma unroll
    for (int k = 0; k < 10; ++k)
      t[k] += (double)XtGp[((size_t)part * 10 + k) * L_VAR + l];
    g2 += (double)GGp[(size_t)part * L_VAR + l];
  }
  double corr = 0.0;
  #pragma unroll
  for (int k = 0; k < 10; ++k) {
    double a = 0.0;
    #pragma unroll
    for (int j = 0; j < 10; ++j) a += Mi[k * 10 + j] * t[j];
    corr += a * t[k];
  }
  gg[l] = (float)(g2 - corr);
}

// ======= K4 (1024 thr): per-permutation shuffle + residualized Yt =============
// Register-resident bitonic (10 LDS passes). Round-12b: old k3t fused as role
// blocks 200..209 (1 l per thread, 10x1024 >= LPAD) -- runs on idle CUs
// concurrently with the 200 sort blocks; k5f reads rgg (round-8 epilogue).
#define CEX(v, s, up) { \
  unsigned long long o_ = __shfl_xor((v), (s), 64); \
  bool lower_ = ((lane & (s)) == 0); \
  bool mn_ = (lower_ == (up)); \
  unsigned long long lo_ = ((v) < o_) ? (v) : o_; \
  unsigned long long hi_ = ((v) < o_) ? o_ : (v); \
  (v) = mn_ ? lo_ : hi_; }

#define CEXP(v0, v1, up) { \
  unsigned long long lo_ = ((v0) < (v1)) ? (v0) : (v1); \
  unsigned long long hi_ = ((v0) < (v1)) ? (v1) : (v0); \
  (v0) = (up) ? lo_ : hi_; (v1) = (up) ? hi_ : lo_; }

__global__ __launch_bounds__(1024) void k4_perm(
    const float* __restrict__ y, const float* __restrict__ offs,
    const float* __restrict__ Xt, const unsigned* __restrict__ pkeys,
    const double* __restrict__ Mi, float* __restrict__ Yt,
    float* __restrict__ yty, unsigned* __restrict__ s,
    unsigned short* __restrict__ yhi, unsigned short* __restrict__ ylo,
    const float* __restrict__ XtGp2, const float* __restrict__ GGp2,
    float* __restrict__ rgg) {
  __shared__ unsigned long long arrA[2048];   // sort 1 keys
  __shared__ unsigned long long arrB[2048];   // sort 2 keys
  __shared__ float yp[2000];
  __shared__ double redL[16][10];
  __shared__ double wf[10];
  __shared__ double red16[16];
  __shared__ double mvd[10];
  __shared__ unsigned ksh[4];
  const int NT = 1024;
  int r = blockIdx.x, tid = threadIdx.x;
  int wid = tid >> 6, lane = tid & 63;

  if (r >= R_PERM) {
    // fused k3t role blocks: l = (r-R_PERM)*1024 + tid  (covers LPAD=10048)
    if (rgg) {
      int l = (r - R_PERM) * 1024 + tid;
      if (l < LPAD) {
        double t[10]; double g2d = 0.0;
        #pragma unroll
        for (int k = 0; k < 10; ++k) t[k] = 0.0;
        for (int part = 0; part < 16; ++part) {
          #pragma unroll
          for (int k = 0; k < 10; ++k)
            t[k] += (double)XtGp2[((size_t)part * 10 + k) * LPAD + l];
          g2d += (double)GGp2[(size_t)part * LPAD + l];
        }
        double corr = 0.0;
        #pragma unroll
        for (int k = 0; k < 10; ++k) {
          double a = 0.0;
          #pragma unroll
          for (int j = 0; j < 10; ++j) a += Mi[k * 10 + j] * t[j];
          corr += a * t[k];
        }
        double v = g2d - corr;
        rgg[l] = (l < L_VAR && v > 0.0) ? (float)(1.0 / v) : 0.f;
      }
    }
    return;
  }

  if (tid == 0) {
    uint32_t phi = pkeys[2 * r], plo = pkeys[2 * r + 1];
#if JAX_THREEFRY_PARTITIONABLE
    uint2 sub1 = tf2(phi, plo, 0u, 1u);
    uint2 key1 = tf2(phi, plo, 0u, 0u);
    uint2 sub2 = tf2(key1.x, key1.y, 0u, 1u);
#else
    uint2 a0k = tf2(phi, plo, 0u, 2u), a1k = tf2(phi, plo, 1u, 3u);
    uint2 key1 = make_uint2(a0k.x, a1k.x);
    uint2 sub1 = make_uint2(a0k.y, a1k.y);
    uint2 b0k = tf2(key1.x, key1.y, 0u, 2u), b1k = tf2(key1.x, key1.y, 1u, 3u);
    uint2 sub2 = make_uint2(b0k.y, b1k.y);
#endif
    ksh[0] = sub1.x; ksh[1] = sub1.y; ksh[2] = sub2.x; ksh[3] = sub2.y;
  }
  __syncthreads();
  uint32_t s1x = ksh[0], s1y = ksh[1], s2x = ksh[2], s2y = ksh[3];

  int e0 = 128 * wid + lane;     // always < 2000
  int e1 = e0 + 64;              // >= 2000 only for wid 15, lane >= 16
  unsigned long long a0 = keyfor(s1x, s1y, e0), a1 = keyfor(s1x, s1y, e1);
  unsigned long long b0 = keyfor(s2x, s2y, e0), b1 = keyfor(s2x, s2y, e1);

  // ---- sizes 2..32 ----
  #pragma unroll
  for (int size = 2; size <= 32; size <<= 1) {
    for (int st = size >> 1; st > 0; st >>= 1) {
      bool up = ((lane & size) == 0);
      CEX(a0, st, up); CEX(a1, st, up);
      CEX(b0, st, up); CEX(b1, st, up);
    }
  }
  // ---- size 64 ----
  #pragma unroll
  for (int st = 32; st > 0; st >>= 1) {
    CEX(a0, st, true);  CEX(b0, st, true);
    CEX(a1, st, false); CEX(b1, st, false);
  }
  // ---- size 128 ----
  {
    bool up = ((wid & 1) == 0);
    CEXP(a0, a1, up); CEXP(b0, b1, up);
    #pragma unroll
    for (int st = 32; st > 0; st >>= 1) {
      CEX(a0, st, up); CEX(a1, st, up);
      CEX(b0, st, up); CEX(b1, st, up);
    }
  }
  // ---- sizes 256..2048 ----
  for (int size = 256; size <= 2048; size <<= 1) {
    arrA[e0] = a0; arrA[e1] = a1;
    arrB[e0] = b0; arrB[e1] = b1;
    __syncthreads();
    for (int st = size >> 1; st >= 128; st >>= 1) {
      int i = 2 * tid - (tid & (st - 1));
      int j = i + st;
      bool up2 = ((i & size) == 0);
      unsigned long long x0 = arrA[i], x1 = arrA[j];
      unsigned long long z0 = arrB[i], z1 = arrB[j];
      bool swA = up2 ? (x0 > x1) : (x0 < x1);
      bool swB = up2 ? (z0 > z1) : (z0 < z1);
      if (swA) { arrA[i] = x1; arrA[j] = x0; }
      if (swB) { arrB[i] = z1; arrB[j] = z0; }
      __syncthreads();
    }
    a0 = arrA[e0]; a1 = arrA[e1];
    b0 = arrB[e0]; b1 = arrB[e1];
    bool up = (((unsigned)(128 * wid) & (unsigned)size) == 0);
    CEXP(a0, a1, up); CEXP(b0, b1, up);
    #pragma unroll
    for (int st = 32; st > 0; st >>= 1) {
      CEX(a0, st, up); CEX(a1, st, up);
      CEX(b0, st, up); CEX(b1, st, up);
    }
  }

  // store sorted A for random access; B stays in registers
  arrA[e0] = a0; arrA[e1] = a1;
  __syncthreads();

  // compose permutations: fin = sortA_idx[ sortB_idx[i] ]
  {
    int s2i0 = (int)(b0 & 2047u);
    int fin0 = (int)(arrA[s2i0] & 2047u);
    yp[e0] = y[fin0] - offs[e0];
    if (e1 < N_SAMP) {
      int s2i1 = (int)(b1 & 2047u);
      int fin1 = (int)(arrA[s2i1] & 2047u);
      yp[e1] = y[fin1] - offs[e1];
    }
  }
  __syncthreads();

  // w = Xt * yp  (10 components, single-barrier reduce)
  double wloc[10];
  #pragma unroll
  for (int k = 0; k < 10; ++k) wloc[k] = 0.0;
  for (int i = tid; i < N_SAMP; i += NT) {
    double v = (double)yp[i];
    #pragma unroll
    for (int k = 0; k < 10; ++k) wloc[k] += (double)Xt[k * N_SAMP + i] * v;
  }
  #pragma unroll
  for (int k = 0; k < 10; ++k) {
    double v = wloc[k];
    #pragma unroll
    for (int off = 32; off > 0; off >>= 1) v += __shfl_xor(v, off, 64);
    if (lane == 0) redL[wid][k] = v;
  }
  __syncthreads();
  if (tid < 10) {
    double t = 0.0;
    for (int w2 = 0; w2 < 16; ++w2) t += redL[w2][tid];
    wf[tid] = t;
  }
  __syncthreads();
  if (tid < 10) {
    double m = 0.0;
    #pragma unroll
    for (int k = 0; k < 10; ++k) m += Mi[tid * 10 + k] * wf[k];
    mvd[tid] = m;
  }
  __syncthreads();

  // residualize + yty
  double acc = 0.0;
  for (int i = tid; i < N_SAMP; i += NT) {
    double d = (double)yp[i];
    #pragma unroll
    for (int k = 0; k < 10; ++k) d -= (double)Xt[k * N_SAMP + i] * mvd[k];
    float v = (float)d;
    if (Yt) Yt[(size_t)r * N_SAMP + i] = v;
    yp[i] = v;
    acc += (double)v * (double)v;
  }
  #pragma unroll
  for (int off = 32; off > 0; off >>= 1) acc += __shfl_xor(acc, off, 64);
  if (lane == 0) red16[wid] = acc;
  __syncthreads();
  if (tid == 0) {
    double tot = 0.0;
    for (int w2 = 0; w2 < 16; ++w2) tot += red16[w2];
    yty[r] = (float)tot;
    s[r] = 0u;
  }

  __syncthreads();
  if (yhi) {
    for (int i = tid; i < KPAD; i += NT) {
      float v = (i < N_SAMP) ? yp[i] : 0.f;
      unsigned short h, l;
      bf16split(v, h, l);
      yhi[(size_t)r * KPAD + i] = h;
      ylo[(size_t)r * KPAD + i] = l;
    }
  }
}

// ================= K5 (fallback): fp32 VALU GEMM ==============================
__global__ __launch_bounds__(256) void k5_gemm(
    const float* __restrict__ G, const float* __restrict__ Yt,
    const float* __restrict__ gg, unsigned* __restrict__ s) {
  __shared__ float As[16][64];
  __shared__ float Bs[16][68];
  int tid = threadIdx.x;
  int tx = tid & 15, ty = tid >> 4;
  int l0 = blockIdx.x * 64, r0 = blockIdx.y * 64;
  int a_row = tid >> 4;
  int a_col = (tid & 15) * 4;
  int b_row = tid >> 2;
  int b_col = (tid & 3) * 4;
  int gl = l0 + a_col;
  bool aval = (gl < L_VAR);
  int gr = r0 + b_row;
  bool bval = (gr < R_PERM);
  const float* gbase = G + (size_t)a_row * L_VAR + gl;
  const float* ybase = Yt + (size_t)gr * N_SAMP + b_col;

  float4 aR = aval ? *(const float4*)gbase : make_float4(0.f, 0.f, 0.f, 0.f);
  float4 bR = bval ? *(const float4*)ybase : make_float4(0.f, 0.f, 0.f, 0.f);

  float acc[4][4];
  #pragma unroll
  for (int u = 0; u < 4; ++u)
    #pragma unroll
    for (int v = 0; v < 4; ++v) acc[u][v] = 0.f;

  for (int i0 = 0; i0 < N_SAMP; i0 += 16) {
    *(float4*)&As[a_row][a_col] = aR;
    Bs[b_col + 0][b_row] = bR.x;
    Bs[b_col + 1][b_row] = bR.y;
    Bs[b_col + 2][b_row] = bR.z;
    Bs[b_col + 3][b_row] = bR.w;
    __syncthreads();
    int inext = i0 + 16;
    if (inext < N_SAMP) {
      aR = aval ? *(const float4*)(gbase + (size_t)inext * L_VAR) : make_float4(0.f, 0.f, 0.f, 0.f);
      bR = bval ? *(const float4*)(ybase + inext) : make_float4(0.f, 0.f, 0.f, 0.f);
    }
    #pragma unroll
    for (int k = 0; k < 16; ++k) {
      float4 av = *(const float4*)&As[k][tx * 4];
      float4 bv = *(const float4*)&Bs[k][ty * 4];
      float a4[4] = {av.x, av.y, av.z, av.w};
      float b4[4] = {bv.x, bv.y, bv.z, bv.w};
      #pragma unroll
      for (int u = 0; u < 4; ++u)
        #pragma unroll
        for (int v = 0; v < 4; ++v)
          acc[u][v] = fmaf(a4[u], b4[v], acc[u][v]);
    }
    __syncthreads();
  }
  #pragma unroll
  for (int v = 0; v < 4; ++v) {
    int rr = r0 + ty * 4 + v;
    float m = 0.f;
    #pragma unroll
    for (int u = 0; u < 4; ++u) {
      int ll = l0 + tx * 4 + u;
      if (ll < L_VAR) {
        float U = acc[u][v];
        float t = U * U / gg[ll];
        m = fmaxf(m, t);
      }
    }
    #pragma unroll
    for (int off = 8; off > 0; off >>= 1) m = fmaxf(m, __shfl_xor(m, off, 64));
    if (tx == 0 && rr < R_PERM) atomicMax(&s[rr], __float_as_uint(m));
  }
}

// ===== K5F (big): 3-deep pipelined bf16x3 MFMA GEMM (round-8 best config) =====
// Tile 64l x 128r, grid 314, LDS 72 KB, triple-buffered, raw s_barrier +
// counted s_waitcnt vmcnt(12). rgg read from buffer (computed in k4 role blocks).
__device__ __forceinline__ void k5f_stage(
    int w, int lane, int kb, int l0, int rbase,
    const unsigned short* __restrict__ GTHI, const unsigned short* __restrict__ GTLO,
    const unsigned short* __restrict__ YHI, const unsigned short* __restrict__ YLO,
    unsigned short* Ah, unsigned short* Al, unsigned short* Bh, unsigned short* Bl) {
  int sub = lane >> 2, kq = lane & 3;
  #pragma unroll
  for (int j = 0; j < 6; ++j) {
    int c = w * 6 + j;
    const unsigned short* src;
    unsigned short* dst;
    if (c < 4) {
      src = GTHI + (size_t)(l0 + c * 16 + sub) * KPAD + kb + kq * 8;
      dst = Ah + c * 512 + lane * 8;
    } else if (c < 8) {
      src = GTLO + (size_t)(l0 + (c - 4) * 16 + sub) * KPAD + kb + kq * 8;
      dst = Al + (c - 4) * 512 + lane * 8;
    } else if (c < 16) {
      src = YHI + (size_t)(rbase + (c - 8) * 16 + sub) * KPAD + kb + kq * 8;
      dst = Bh + (c - 8) * 512 + lane * 8;
    } else {
      src = YLO + (size_t)(rbase + (c - 16) * 16 + sub) * KPAD + kb + kq * 8;
      dst = Bl + (c - 16) * 512 + lane * 8;
    }
    __builtin_amdgcn_global_load_lds(
        (const __attribute__((address_space(1))) unsigned int*)(const void*)src,
        (__attribute__((address_space(3))) unsigned int*)(void*)dst, 16, 0, 0);
  }
}

__global__ __launch_bounds__(256) void k5f_mfma(
    const unsigned short* __restrict__ GTHI, const unsigned short* __restrict__ GTLO,
    const unsigned short* __restrict__ YHI, const unsigned short* __restrict__ YLO,
    const float* __restrict__ rgg, unsigned* __restrict__ s) {
  __shared__ unsigned short Ah[3][64 * 32];
  __shared__ unsigned short Al[3][64 * 32];
  __shared__ unsigned short Bh[3][128 * 32];
  __shared__ unsigned short Bl[3][128 * 32];
  int tid = threadIdx.x;
  int w = tid >> 6, lane = tid & 63;
  int row16 = lane & 15, quad = lane >> 4;
  int ltile = blockIdx.x >> 1;
  int rhalf = blockIdx.x & 1;
  int l0 = ltile * 64;
  int rbase = rhalf * 128;

  float4v acc[4][2];
  #pragma unroll
  for (int mt = 0; mt < 4; ++mt)
    #pragma unroll
    for (int nt = 0; nt < 2; ++nt)
      acc[mt][nt] = (float4v){0.f, 0.f, 0.f, 0.f};

  // prologue: fill the 3-deep pipeline (18 outstanding loads per wave)
  k5f_stage(w, lane, 0,  l0, rbase, GTHI, GTLO, YHI, YLO, Ah[0], Al[0], Bh[0], Bl[0]);
  k5f_stage(w, lane, 32, l0, rbase, GTHI, GTLO, YHI, YLO, Ah[1], Al[1], Bh[1], Bl[1]);
  k5f_stage(w, lane, 64, l0, rbase, GTHI, GTLO, YHI, YLO, Ah[2], Al[2], Bh[2], Bl[2]);

  #pragma unroll 1
  for (int step = 0; step < 64; ++step) {
    int cur = step % 3;
    // wait for THIS step's 6 per-wave loads (oldest); keep up to 12 in flight.
    if (step < 62) {
      asm volatile("s_waitcnt vmcnt(12)" ::: "memory");
    } else if (step == 62) {
      asm volatile("s_waitcnt vmcnt(6)" ::: "memory");
    } else {
      asm volatile("s_waitcnt vmcnt(0)" ::: "memory");
    }
    __builtin_amdgcn_s_barrier();   // all waves' step data now visible
    __builtin_amdgcn_sched_barrier(0);

    short8v ahf[4], alf[4], bhf[2], blf[2];
    #pragma unroll
    for (int mt = 0; mt < 4; ++mt) {
      int o = (mt * 16 + row16) * 32 + quad * 8;
      ahf[mt] = *(const short8v*)&Ah[cur][o];
      alf[mt] = *(const short8v*)&Al[cur][o];
    }
    #pragma unroll
    for (int nt = 0; nt < 2; ++nt) {
      int o = (w * 32 + nt * 16 + row16) * 32 + quad * 8;
      bhf[nt] = *(const short8v*)&Bh[cur][o];
      blf[nt] = *(const short8v*)&Bl[cur][o];
    }
    #pragma unroll
    for (int nt = 0; nt < 2; ++nt) {
      #pragma unroll
      for (int mt = 0; mt < 4; ++mt) {
        acc[mt][nt] = __builtin_amdgcn_mfma_f32_16x16x32_bf16(ahf[mt], bhf[nt], acc[mt][nt], 0, 0, 0);
        acc[mt][nt] = __builtin_amdgcn_mfma_f32_16x16x32_bf16(ahf[mt], blf[nt], acc[mt][nt], 0, 0, 0);
        acc[mt][nt] = __builtin_amdgcn_mfma_f32_16x16x32_bf16(alf[mt], bhf[nt], acc[mt][nt], 0, 0, 0);
      }
    }
    // all waves done READING buf[cur]; refill it with step+3.
    __builtin_amdgcn_s_barrier();
    if (step + 3 < 64)
      k5f_stage(w, lane, (step + 3) * 32, l0, rbase, GTHI, GTLO, YHI, YLO,
                Ah[cur], Al[cur], Bh[cur], Bl[cur]);
  }

  // epilogue: wave owns 64l x 32r at (l0, rbase + w*32)
  float rl_[4][4];
  #pragma unroll
  for (int mt = 0; mt < 4; ++mt)
    #pragma unroll
    for (int q = 0; q < 4; ++q)
      rl_[mt][q] = rgg[l0 + mt * 16 + quad * 4 + q];
  #pragma unroll
  for (int nt = 0; nt < 2; ++nt) {
    float m = 0.f;
    #pragma unroll
    for (int mt = 0; mt < 4; ++mt)
      #pragma unroll
      for (int q = 0; q < 4; ++q) {
        float U = acc[mt][nt][q];
        m = fmaxf(m, U * U * rl_[mt][q]);
      }
    m = fmaxf(m, __shfl_xor(m, 16, 64));
    m = fmaxf(m, __shfl_xor(m, 32, 64));
    int r = rbase + w * 32 + nt * 16 + row16;
    if (quad == 0 && r < R_PERM) atomicMax(&s[r], __float_as_uint(m));
  }
}

// ================= K6: TS^2 -> p -> MoM + lane-parallel Newton -> betainc =====
__global__ __launch_bounds__(256) void k6_final(
    const unsigned* __restrict__ sbits, const float* __restrict__ yty,
    const float* __restrict__ minp, float* __restrict__ out) {
  __shared__ double red[256];
  int tid = threadIdx.x;
  double p = 0.0, p2 = 0.0, lp = 0.0, l1p = 0.0;
  if (tid < R_PERM) {
    double t = (double)__uint_as_float(sbits[tid]);
    double Y = (double)yty[tid];
    double ts2 = DOF_D * t / (Y - t);
    double pp = erfc(sqrt(0.5 * ts2));
    p = pp; p2 = pp * pp; lp = log(pp); l1p = log1p(-pp);
  }
  double Sp  = breduce_add(p, red, tid);
  double Sp2 = breduce_add(p2, red, tid);
  double S1  = breduce_add(lp, red, tid);
  double S2  = breduce_add(l1p, red, tid);
  if (tid < 64) {
    const double nobs = (double)R_PERM;
    double mean = Sp / nobs;
    double var = Sp2 / nobs - mean * mean;
    double k = mean * (mean * (1.0 - mean) / var - 1.0);
    double n = k * (1.0 / mean - 1.0);
    double old_lik = 10000.0, diff = 1000.0;
    int iter = 0;
    int sel = tid % 3, grp = tid / 3;
    while (fabs(diff) > 1e-3 && iter <= 100) {
      double arg = (sel == 0) ? k : (sel == 1) ? n : (k + n);
      double v = 0.0;
      if (grp == 0) v = dg_trigamma(arg);
      else if (grp == 1) v = dg_tetragamma(arg);
      else if (grp == 2) v = dg_digamma(arg);
      double pg1k = __shfl(v, 0, 64), pg1n = __shfl(v, 1, 64), pg1kn = __shfl(v, 2, 64);
      double pg2k = __shfl(v, 3, 64), pg2n = __shfl(v, 4, 64), pg2kn = __shfl(v, 5, 64);
      double dgk  = __shfl(v, 6, 64), dgn  = __shfl(v, 7, 64), dgkn  = __shfl(v, 8, 64);
      double i_kn = -pg1kn, i_k = pg1k + i_kn, i_n = pg1n + i_kn;
      double A = -nobs * i_k, B = -nobs * i_kn, C = -nobs * i_n;
      double s0 = S1 - nobs * (dgk - dgkn);
      double s1 = S2 - nobs * (dgn - dgkn);
      double det = A * C - B * B;
      double d0 = (C * s0 - B * s1) / det;
      double d1 = (A * s1 - B * s0) / det;
      double i_kkn = pg1n * pg2kn;
      double g_k = -pg1n * pg2k + i_kkn + pg1kn * pg2k;
      double i_knn = i_kkn - pg1kn * pg2n;
      double i_nnk = pg1k * pg2kn;
      double i_nkk = i_nnk - pg1kn * pg2k;
      double g_n = -pg1k * pg2n + i_nnk + pg1kn * pg2n;
      double scale = -pg1k * pg1n + (pg1k + pg1n) * pg1kn;
      double f = 0.5 / scale;
      double adj0 = f * (g_k * d0 * d0 + 2.0 * i_kkn * d0 * d1 + i_knn * d1 * d1);
      double adj1 = f * (i_nkk * d0 * d0 + 2.0 * i_nnk * d0 * d1 + g_n * d1 * d1);
      double nk_ = k - d0 - 0.5 * adj0;
      double nn_ = n - d1 - 0.5 * adj1;
      double arg2 = (tid == 0) ? nk_ : (tid == 1) ? nn_ : (nk_ + nn_);
      double lg = (tid < 3) ? lgamma(arg2) : 0.0;
      double lgk = __shfl(lg, 0, 64), lgn = __shfl(lg, 1, 64), lgkn = __shfl(lg, 2, 64);
      double nl = (nk_ - 1.0) * S1 + (nn_ - 1.0) * S2 - nobs * (lgk + lgn - lgkn);
      diff = old_lik - nl;
      old_lik = nl; k = nk_; n = nn_; ++iter;
    }
    if (tid == 0) {
      double conv = (fabs(diff) < 1e-3 && iter <= 100) ? 1.0 : 0.0;
      double adj = betainc_d(k, n, (double)(*minp));
      out[0] = (float)adj;
      out[1] = (float)k;
      out[2] = (float)n;
      out[3] = (float)conv;
    }
  }
}

__global__ void k_err(float* out) {
  if (threadIdx.x < 4) out[threadIdx.x] = -12345.0f;
}

extern "C" void kernel_launch(void* const* d_in, const int* in_sizes, int n_in,
                              void* d_out, int out_size, void* d_ws, size_t ws_size,
                              hipStream_t stream) {
  const float* X     = (const float*)d_in[0];
  const float* y     = (const float*)d_in[1];
  const float* G     = (const float*)d_in[2];
  const float* obs_p = (const float*)d_in[3];
  const float* offs  = (const float*)d_in[4];
  const int*   seedp = (const int*)d_in[5];
  float* out = (float*)d_out;

  if (ws_size < WS_OLD) {
    k_err<<<1, 64, 0, stream>>>(out);
    return;
  }
  char* ws = (char*)d_ws;
  unsigned* pkeys = (unsigned*)(ws + OFF_PKEYS);
  double*   Mi    = (double*)(ws + OFF_MI);
  float*    minp  = (float*)(ws + OFF_MINP);
  float*    Xt    = (float*)(ws + OFF_XT);
  float*    XtGp  = (float*)(ws + OFF_XTGP);
  float*    GGp   = (float*)(ws + OFF_GGP);
  float*    gg    = (float*)(ws + OFF_GG);
  float*    yty   = (float*)(ws + OFF_YTY);
  unsigned* s     = (unsigned*)(ws + OFF_S);
  float*    Yt    = (float*)(ws + OFF_YT);

  bool big = (ws_size >= WS_BIG);
  float*          rgg   = big ? (float*)(ws + OFF_RGG) : nullptr;
  unsigned short* yhi   = big ? (unsigned short*)(ws + OFF_YHI) : nullptr;
  unsigned short* ylo   = big ? (unsigned short*)(ws + OFF_YLO) : nullptr;
  float*          XtGp2 = big ? (float*)(ws + OFF_XTGP2) : nullptr;
  float*          GGp2  = big ? (float*)(ws + OFF_GGP2) : nullptr;
  unsigned short* GTHI  = big ? (unsigned short*)(ws + OFF_GTHI) : nullptr;
  unsigned short* GTLO  = big ? (unsigned short*)(ws + OFF_GTLO) : nullptr;

  if (big) {
    // k1's 59 role-blocks fused into k2t (x in [158,217), y==0) -> one launch
    k2t_pass<<<dim3(158 + 59, 16), 256, 0, stream>>>(
        G, X, obs_p, seedp, GTHI, GTLO, XtGp2, GGp2, pkeys,
        Xt, Mi, minp, yhi, ylo);
    // k3t fused as k4 role blocks 200..209 (runs on idle CUs under the sort)
    k4_perm<<<R_PERM + 10, 1024, 0, stream>>>(
        y, offs, Xt, pkeys, Mi, nullptr, yty, s, yhi, ylo, XtGp2, GGp2, rgg);
    k5f_mfma<<<314, 256, 0, stream>>>(GTHI, GTLO, yhi, ylo, rgg, s);
  } else {
    k1_setup<<<3, 256, 0, stream>>>(X, obs_p, Xt, Mi, minp, nullptr, nullptr);
    k2_xtg<<<dim3(41, 5), 256, 0, stream>>>(G, X, seedp, XtGp, GGp, pkeys);
    k3_gg<<<40, 256, 0, stream>>>(XtGp, GGp, Mi, gg);
    k4_perm<<<R_PERM, 1024, 0, stream>>>(y, offs, Xt, pkeys, Mi, Yt, yty, s,
                                         nullptr, nullptr, nullptr, nullptr, nullptr);
    k5_gemm<<<dim3(157, 4), 256, 0, stream>>>(G, Yt, gg, s);
  }
  k6_final<<<1, 256, 0, stream>>>(s, yty, minp, out);
}